// Round 7
// baseline (944.161 us; speedup 1.0000x reference)
//
#include <hip/hip_runtime.h>
#include <hip/hip_bf16.h>

typedef unsigned short u16;
typedef unsigned int   u32;
typedef __attribute__((ext_vector_type(8))) short bf16x8;
typedef __attribute__((ext_vector_type(4))) float f32x4;
typedef __attribute__((ext_vector_type(4))) u16   u16x4;

constexpr int TT  = 2;
constexpr int NN  = 16384;
constexpr int EE  = 262144;

__device__ __forceinline__ u16 f2b(float f){
  u32 x = __float_as_uint(f);
  u32 r = (x + 0x7fffu + ((x >> 16) & 1u)) >> 16;
  return (u16)r;
}
__device__ __forceinline__ float b2f(u16 u){ return __uint_as_float(((u32)u) << 16); }
__device__ __forceinline__ u32 pack2bf(float a, float b){
  __hip_bfloat162 h = __float22bfloat162_rn(make_float2(a, b));
  union { __hip_bfloat162 h2; u32 u; } cv; cv.h2 = h; return cv.u;
}

// XOR-swizzled LDS addressing for stride-64 (u16) tiles: col c (multiple of 4/8)
// stored at c ^ ((row&7)*8). b128 fragment reads land 2 rows per 4-bank group
// -> 2-way aliasing, which is free on gfx950 (m136). Saves all padding bytes.
__device__ __forceinline__ int swz64(int row, int c){
  return (row << 6) + (c ^ ((row & 7) << 3));
}

__device__ __forceinline__ float fast_tanh(float u){
  return 1.f - 2.f*__builtin_amdgcn_rcpf(1.f + __expf(2.f*u));
}
__device__ __forceinline__ float gelu_f(float x){
  float u = 0.7978845608028654f * (x + 0.044715f * x*x*x);
  return 0.5f * x * (1.f + fast_tanh(u));
}

// ---------------- CSR build ----------------
__global__ void csr_hist(const int* __restrict__ dst, int* __restrict__ cnt){
  int id = blockIdx.x*256 + threadIdx.x;
  int e = id >> 18;
  atomicAdd(&cnt[e*NN + dst[id]], 1);
}

__global__ void csr_scan(const int* __restrict__ cnt, int* __restrict__ offs){
  const int e = blockIdx.x, tid = threadIdx.x;
  const int CH = NN/256;
  const int* c = cnt + e*NN;
  int* of = offs + e*(NN+1);
  const int base = tid*CH;
  int s = 0;
  for(int i=0;i<CH;i++) s += c[base+i];
  __shared__ int sm[256];
  sm[tid] = s; __syncthreads();
  for(int o=1;o<256;o<<=1){
    int v = (tid>=o) ? sm[tid-o] : 0;
    __syncthreads();
    sm[tid] += v;
    __syncthreads();
  }
  int run = sm[tid] - s;
  for(int i=0;i<CH;i++){ of[base+i] = run; run += c[base+i]; }
  if(tid==255) of[NN] = run;
}

__global__ void csr_scatter(const int* __restrict__ dst, const int* __restrict__ src,
                            const int* __restrict__ offs, int* __restrict__ cur,
                            int* __restrict__ elist){
  int id = blockIdx.x*256 + threadIdx.x;
  int e = id >> 18;
  int d = dst[id];
  int pos = offs[e*(NN+1)+d] + atomicAdd(&cur[e*NN+d], 1);
  elist[e*EE + pos] = src[id];
}

// ---------------- transpose + bf16 convert (weights) ----------------
__global__ void tconv(const float* __restrict__ in, u16* __restrict__ out, int K, int Nc){
  __shared__ float tile[32][33];
  const long base = (long)blockIdx.z * K * Nc;
  const int k0 = blockIdx.x*32, n0 = blockIdx.y*32;
  const int tx = threadIdx.x, ty = threadIdx.y;
  for(int i=0;i<32;i+=8)
    tile[ty+i][tx] = in[base + (long)(k0+ty+i)*Nc + n0+tx];
  __syncthreads();
  for(int i=0;i<32;i+=8)
    out[base + (long)(n0+ty+i)*K + k0+tx] = f2b(tile[tx][ty+i]);
}

// ---------------- fold head transforms into K/V weights ----------------
__global__ void eff_w(const float* __restrict__ kw, const float* __restrict__ vw,
                      const float* __restrict__ kb, const float* __restrict__ vb,
                      const float* __restrict__ att, const float* __restrict__ val,
                      u16* __restrict__ qkvwt, float* __restrict__ qkvb){
  const int h = blockIdx.x, lt = blockIdx.y, kv = blockIdx.z;   // 8 x 4 x 2
  const int l = lt >> 1;
  const float* W = (kv ? vw : kw) + (long)lt*65536;
  const float* A = (kv ? val : att) + (long)lt*8192 + h*1024;
  const float* B = (kv ? vb : kb) + (long)lt*256 + h*32;
  __shared__ float As[32][33];
  for(int idx=threadIdx.x; idx<1024; idx+=256) As[idx>>5][idx&31] = A[idx];
  __syncthreads();
  const int r = threadIdx.x;
  float x[32];
  const float* wr = W + (long)r*256 + h*32;
  #pragma unroll
  for(int i=0;i<32;i++) x[i] = wr[i];
  u16* outb = qkvwt + (kv ? 524288 : 0) + (long)lt*65536;
  #pragma unroll 4
  for(int j=0;j<32;j++){
    float s = 0.f;
    #pragma unroll
    for(int i=0;i<32;i++) s = fmaf(x[i], As[i][j], s);
    outb[(h*32 + j)*256 + r] = f2b(s);
  }
  if (r < 32){
    float s = 0.f;
    #pragma unroll
    for(int i=0;i<32;i++) s = fmaf(B[i], As[i][r], s);
    qkvb[l*1536 + (kv ? 1024 : 0) + (lt&1)*256 + h*32 + r] = s;
  }
}

__global__ void pack_qb(const float* __restrict__ qb, float* __restrict__ qkvb){
  int i = blockIdx.x*256 + threadIdx.x;   // 1024 = L*T*256
  int l = i >> 9, r = i & 511;
  qkvb[l*1536 + 512 + r] = qb[l*512 + r];
}

// ---------------- rank-1 precompute for the linear posvect block ----------------
__global__ void uv_k(const float* __restrict__ lw, const float* __restrict__ lb,
                     const float* __restrict__ fcw,
                     float* __restrict__ ubuf, float* __restrict__ vbuf){
  const int by = blockIdx.x;            // 12
  const int j  = threadIdx.x;           // 256
  const float* fw = fcw + ((long)by*1024 + 256)*256 + j;
  const float* lwp = lw + by*256;
  const float* lbp = lb + by*256;
  float u = 0.f, v = 0.f;
  for(int h=0; h<256; h++){
    const float f = fw[(long)h*256];
    u = fmaf(lwp[h], f, u);
    v = fmaf(lbp[h], f, v);
  }
  ubuf[by*256+j] = u; vbuf[by*256+j] = v;
}

// ---------------- generic bf16-MFMA GEMM (XOR-swizzled LDS, 40KB -> 4 blocks/CU) ----
// EPI: 0 = fp32 +bias; 1 = gelu->bf16; 4 = tanh dot w2 row-sum; 5 = residual mix + LayerNorm
// ASRC: 0 = fp32 A; 1 = bf16 A.  ZQKV: blockIdx.z = {K,Q,V}; K/V -> bf16 KV record, Q -> bf16.
// NOTE: Cv/resid intentionally NOT __restrict__ — EPI5 runs in-place on hbuf.
template<int BM,int BN,int BK,int WM,int WN,int ASRC,int EPI,int ZQKV>
__global__ void __launch_bounds__(256,4)
gemm_k(const void* __restrict__ Av, const u16* __restrict__ Bt,
       const float* __restrict__ bias, void* Cv,
       int K, int lda, int ldc,
       long strideA, long strideB, long strideBias, long strideC,
       const float* resid, const float* __restrict__ resgate,
       const int* __restrict__ selp, u16* __restrict__ kvout,
       const float* __restrict__ lng, const float* __restrict__ lnb)
{
  static_assert(BK == 64, "swizzle assumes BK=64");
  constexpr int WTM = BM/WM, WTN = BN/WN;
  constexpr int RM = WTM/16, RN = WTN/16;
  __shared__ u16 lA[BM*64];
  __shared__ u16 lB[BN*64];

  const int tid = threadIdx.x;
  const int by  = blockIdx.y;
  const int m0  = blockIdx.x * BM;
  const int lane = tid & 63, wvi = tid >> 6;
  const int wr = wvi / WN, wc = wvi % WN;
  const int wr0 = wr * WTM, wc0 = wc * WTN;
  const int l16 = lane & 15, qd = lane >> 4;

  int zq = 0; int boff = 0;
  if constexpr (ZQKV){
    zq = blockIdx.z;
    boff = zq*512;
  }

  long aoff = (long)by * strideA;
  if (selp) aoff += (long)selp[0] * strideA;
  const float* A32 = (const float*)Av;
  const u16*   A16 = (const u16*)Av;
  const u16*   Bp  = Bt + (long)by * strideB + (long)zq * 262144;

  f32x4 acc[RM][RN];
  #pragma unroll
  for(int i=0;i<RM;i++)
    #pragma unroll
    for(int j=0;j<RN;j++) acc[i][j] = (f32x4){0.f,0.f,0.f,0.f};

  for(int k0=0;k0<K;k0+=BK){
    if constexpr (ASRC == 0){
      for(int idx=tid; idx < BM*16; idx += 256){
        int r = idx >> 4, c = (idx & 15)*4;
        const float4 v = *(const float4*)(A32 + aoff + (long)(m0+r)*lda + k0 + c);
        uint2 o2; o2.x = pack2bf(v.x, v.y); o2.y = pack2bf(v.z, v.w);
        *(uint2*)&lA[swz64(r, c)] = o2;
      }
    } else {
      for(int idx=tid; idx < BM*8; idx += 256){
        int r = idx >> 3, c = (idx & 7)*8;
        *(uint4*)&lA[swz64(r, c)] = *(const uint4*)(A16 + aoff + (long)(m0+r)*lda + k0 + c);
      }
    }
    for(int idx=tid; idx < BN*8; idx += 256){
      int n = idx >> 3, c = (idx & 7)*8;
      *(uint4*)&lB[swz64(n, c)] = *(const uint4*)(Bp + (long)n*K + k0 + c);
    }
    __syncthreads();
    #pragma unroll
    for(int ks=0; ks<BK; ks+=32){
      bf16x8 af[RM], bfr[RN];
      #pragma unroll
      for(int i=0;i<RM;i++) af[i]  = *(const bf16x8*)&lA[swz64(wr0 + i*16 + l16, ks + qd*8)];
      #pragma unroll
      for(int j=0;j<RN;j++) bfr[j] = *(const bf16x8*)&lB[swz64(wc0 + j*16 + l16, ks + qd*8)];
      #pragma unroll
      for(int i=0;i<RM;i++)
        #pragma unroll
        for(int j=0;j<RN;j++)
          acc[i][j] = __builtin_amdgcn_mfma_f32_16x16x32_bf16(af[i], bfr[j], acc[i][j], 0,0,0);
    }
    __syncthreads();
  }

  if constexpr (EPI == 4){
    float* rsum = (float*)lA;   // alias dead A-tile: WN*BM floats (fits: BM*128 B)
    #pragma unroll
    for(int i=0;i<RM;i++){
      #pragma unroll
      for(int r=0;r<4;r++){
        float part = 0.f;
        #pragma unroll
        for(int jj=0;jj<RN;jj++){
          const int col = wc0 + jj*16 + l16;
          const float v = fast_tanh(acc[i][jj][r] + bias[boff + col]);
          part += v * resid[col];
        }
        part += __shfl_xor(part,1); part += __shfl_xor(part,2);
        part += __shfl_xor(part,4); part += __shfl_xor(part,8);
        if (l16 == 0) rsum[wc*BM + wr0 + i*16 + qd*4 + r] = part;
      }
    }
    __syncthreads();
    if (tid < BM){
      float s = 0.f;
      #pragma unroll
      for(int w=0;w<WN;w++) s += rsum[w*BM + tid];
      ((float*)Cv)[m0 + tid] = s;
    }
    return;
  } else if constexpr (EPI == 5){
    // residual mix -> LayerNorm fused; Cv == resid buffer (in-place per-row; barrier-separated)
    float* red1 = (float*)lA;            // WN*BM
    float* red2 = red1 + WN*BM;          // WN*BM
    float* muv  = red2 + WN*BM;          // BM*2   (total 2560B < BM*128B lA)
    const float alpha = 1.f/(1.f + __expf(-resgate[by]));
    #pragma unroll
    for(int i=0;i<RM;i++){
      #pragma unroll
      for(int r=0;r<4;r++){
        const int rloc = wr0 + i*16 + qd*4 + r;
        const int row = m0 + rloc;
        float s1 = 0.f, s2 = 0.f;
        #pragma unroll
        for(int j=0;j<RN;j++){
          const int col = wc0 + j*16 + l16;
          float v = acc[i][j][r] + bias[(long)by*strideBias + col];
          const float hv = resid[(long)by*strideC + (long)row*ldc + col];
          v = v*alpha + hv*(1.f - alpha);
          acc[i][j][r] = v;
          s1 += v; s2 += v*v;
        }
        s1 += __shfl_xor(s1,1); s1 += __shfl_xor(s1,2); s1 += __shfl_xor(s1,4); s1 += __shfl_xor(s1,8);
        s2 += __shfl_xor(s2,1); s2 += __shfl_xor(s2,2); s2 += __shfl_xor(s2,4); s2 += __shfl_xor(s2,8);
        if (l16 == 0){ red1[wc*BM + rloc] = s1; red2[wc*BM + rloc] = s2; }
      }
    }
    __syncthreads();
    if (tid < BM){
      float s1 = 0.f, s2 = 0.f;
      #pragma unroll
      for(int w=0;w<WN;w++){ s1 += red1[w*BM + tid]; s2 += red2[w*BM + tid]; }
      const float mu = s1*(1.f/256.f);
      const float var = s2*(1.f/256.f) - mu*mu;
      muv[tid*2]   = mu;
      muv[tid*2+1] = rsqrtf(fmaxf(var, 0.f) + 1e-5f);
    }
    __syncthreads();
    #pragma unroll
    for(int i=0;i<RM;i++){
      #pragma unroll
      for(int r=0;r<4;r++){
        const int rloc = wr0 + i*16 + qd*4 + r;
        const int row = m0 + rloc;
        const float mu = muv[rloc*2], rs = muv[rloc*2+1];
        #pragma unroll
        for(int j=0;j<RN;j++){
          const int col = wc0 + j*16 + l16;
          const float o = (acc[i][j][r]-mu)*rs*lng[by*256+col] + lnb[by*256+col];
          ((float*)Cv)[(long)by*strideC + (long)row*ldc + col] = o;
        }
      }
    }
    return;
  } else {
    #pragma unroll
    for(int i=0;i<RM;i++){
      #pragma unroll
      for(int j=0;j<RN;j++){
        const int col = wc0 + j*16 + l16;
        const float bv = bias[(long)by*strideBias + boff + col];
        #pragma unroll
        for(int r=0;r<4;r++){
          const int row = m0 + wr0 + i*16 + qd*4 + r;
          float v = acc[i][j][r] + bv;
          if constexpr (ZQKV){
            if (zq == 1)
              ((u16*)Cv)[(long)by*strideC + (long)row*ldc + col] = f2b(v);   // Q bf16
            else
              kvout[((long)by*NN + row)*512 + (zq==2 ? 256 : 0) + col] = f2b(v);
          } else {
            const long cidx = (long)by*strideC + (long)row*ldc + col;
            if constexpr (EPI == 0) ((float*)Cv)[cidx] = v;
            else ((u16*)Cv)[cidx] = f2b(gelu_f(v));
          }
        }
      }
    }
  }
}

// ---------------- posvect: K=768, swizzled LDS (48.5KB -> 3 blocks/CU) ----------
__global__ void __launch_bounds__(256,3)
posvect_k(const float* __restrict__ scalars,
          const float* __restrict__ ww, const float* __restrict__ wb,
          const float* __restrict__ sw, const float* __restrict__ sb,
          const float* __restrict__ gw, const float* __restrict__ gb,
          const u16* __restrict__ fwt, const float* __restrict__ fcb,
          const float* __restrict__ ubuf, const float* __restrict__ vbuf,
          u16* __restrict__ zb)
{
  __shared__ u16 lA[128*64];
  __shared__ u16 lB[256*64];
  __shared__ float xs[128];
  const int tid = threadIdx.x;
  const int by = blockIdx.y;
  const int t = by / 6, m = by % 6;
  const int m0 = blockIdx.x * 128;
  const int lane = tid & 63, wvi = tid >> 6;
  const int wc0 = wvi * 64;
  const int l16 = lane & 15, qd = lane >> 4;
  const int pofs = by * 256;

  if (tid < 128) xs[tid] = scalars[((long)t*NN + m0 + tid)*6 + m];

  const u16* Bp = fwt + (long)by * (1024*256);

  f32x4 acc[8][4];
  #pragma unroll
  for(int i=0;i<8;i++)
    #pragma unroll
    for(int j=0;j<4;j++) acc[i][j] = (f32x4){0.f,0.f,0.f,0.f};

  __syncthreads();

  const int jg   = tid & 7;
  const int row0 = tid >> 3;

  for(int kt=0; kt<12; kt++){
    const int k0 = kt*64 + (kt>=4 ? 256 : 0);        // skip the linear slab
    const int ia = (kt<4) ? 0 : ((kt<8) ? 2 : 3);
    const int hh = (k0 & 255) + jg*8;
    const float* wsel = ((ia==0)?ww:(ia==2)?sw:gw) + pofs;
    const float* bsel = ((ia==0)?wb:(ia==2)?sb:gb) + pofs;
    const float4 wa  = *(const float4*)(wsel + hh);
    const float4 wv2 = *(const float4*)(wsel + hh + 4);
    const float4 ba  = *(const float4*)(bsel + hh);
    const float4 bv2 = *(const float4*)(bsel + hh + 4);
    #pragma unroll
    for(int it=0; it<4; it++){
      const int row = row0 + it*32;
      const float x = xs[row];
      float y[8];
      y[0]=fmaf(x,wa.x,ba.x);   y[1]=fmaf(x,wa.y,ba.y);
      y[2]=fmaf(x,wa.z,ba.z);   y[3]=fmaf(x,wa.w,ba.w);
      y[4]=fmaf(x,wv2.x,bv2.x); y[5]=fmaf(x,wv2.y,bv2.y);
      y[6]=fmaf(x,wv2.z,bv2.z); y[7]=fmaf(x,wv2.w,bv2.w);
      float a[8];
      if (ia==0){
        #pragma unroll
        for(int i=0;i<8;i++) a[i] = __sinf(y[i]);
      } else if (ia==2){
        #pragma unroll
        for(int i=0;i<8;i++){
          const float ab = fabsf(y[i]);
          a[i] = fmaxf(y[i],0.f) + __logf(1.f + __expf(-ab));
        }
      } else {
        #pragma unroll
        for(int i=0;i<8;i++)
          a[i] = __builtin_amdgcn_rcpf(1.f + __expf(-y[i]));
      }
      uint4 pv;
      pv.x = pack2bf(a[0],a[1]); pv.y = pack2bf(a[2],a[3]);
      pv.z = pack2bf(a[4],a[5]); pv.w = pack2bf(a[6],a[7]);
      *(uint4*)&lA[swz64(row, jg*8)] = pv;
    }
    for(int idx=tid; idx<2048; idx+=256){
      int n = idx >> 3, c = (idx & 7)*8;
      *(uint4*)&lB[swz64(n, c)] = *(const uint4*)(Bp + (long)n*1024 + k0 + c);
    }
    __syncthreads();
    #pragma unroll
    for(int ks=0; ks<64; ks+=32){
      bf16x8 af[8], bfr[4];
      #pragma unroll
      for(int i=0;i<8;i++) af[i]  = *(const bf16x8*)&lA[swz64(i*16 + l16, ks + qd*8)];
      #pragma unroll
      for(int jj=0;jj<4;jj++) bfr[jj] = *(const bf16x8*)&lB[swz64(wc0 + jj*16 + l16, ks + qd*8)];
      #pragma unroll
      for(int i=0;i<8;i++)
        #pragma unroll
        for(int jj=0;jj<4;jj++)
          acc[i][jj] = __builtin_amdgcn_mfma_f32_16x16x32_bf16(af[i], bfr[jj], acc[i][jj], 0,0,0);
    }
    __syncthreads();
  }

  #pragma unroll
  for(int i=0;i<8;i++){
    #pragma unroll
    for(int jj=0;jj<4;jj++){
      const int col = wc0 + jj*16 + l16;
      const float bv = fcb[pofs + col] + vbuf[pofs + col];
      const float uu = ubuf[pofs + col];
      #pragma unroll
      for(int r=0;r<4;r++){
        const int row = i*16 + qd*4 + r;
        const float v = acc[i][jj][r] + bv + xs[row]*uu;
        zb[((long)t*NN + m0 + row)*1792 + (m+1)*256 + col] = f2b(gelu_f(v));
      }
    }
  }
}

// ---------------- IMA combine ----------------
__global__ void ima_combine(const u16* __restrict__ zb, const float* __restrict__ wbuf,
                            float* __restrict__ H){
  const int row = blockIdx.x*4 + (threadIdx.x>>6);
  const int lane = threadIdx.x & 63;
  const float* w7 = wbuf + (long)row*7;
  float w[7]; float mx = -1e30f;
  #pragma unroll
  for(int m=0;m<7;m++){ w[m] = w7[m]; mx = fmaxf(mx, w[m]); }
  float sum = 0.f;
  #pragma unroll
  for(int m=0;m<7;m++){ w[m] = __expf(w[m]-mx); sum += w[m]; }
  const float inv = __builtin_amdgcn_rcpf(sum);
  float4 acc = {0,0,0,0};
  #pragma unroll
  for(int m=0;m<7;m++){
    const u16x4 z4 = *(const u16x4*)&zb[((long)row*7 + m)*256 + lane*4];
    const float p = w[m]*inv;
    acc.x += p*b2f(z4.x); acc.y += p*b2f(z4.y); acc.z += p*b2f(z4.z); acc.w += p*b2f(z4.w);
  }
  *(float4*)&H[(long)row*256 + lane*4] = acc;
}

// ---------------- attention aggregation: split-lane KV gather, unroll-8 ----------
// lanes 0-31: K dims half*8..+7 (head = half>>2); lanes 32-63: V dims half*8..+7.
__global__ void attn_agg(const u16* __restrict__ Q16, const u16* __restrict__ KV,
                         u16* __restrict__ AGG,
                         const int* __restrict__ offs, const int* __restrict__ elist,
                         const float* __restrict__ canon){
  const int e = blockIdx.y, dt = 1 - e;
  const int d = blockIdx.x*4 + (threadIdx.x>>6);
  const int lane = threadIdx.x & 63;
  const int half = lane & 31;
  const float scale = canon[e*8 + (half>>2)] * 0.17677669529663687f;

  const uint4 qv = *(const uint4*)&Q16[((long)dt*NN + d)*256 + half*8];
  float q[8];
  q[0]=b2f((u16)(qv.x&0xffff)); q[1]=b2f((u16)(qv.x>>16));
  q[2]=b2f((u16)(qv.y&0xffff)); q[3]=b2f((u16)(qv.y>>16));
  q[4]=b2f((u16)(qv.z&0xffff)); q[5]=b2f((u16)(qv.z>>16));
  q[6]=b2f((u16)(qv.w&0xffff)); q[7]=b2f((u16)(qv.w>>16));

  const int p0 = offs[e*(NN+1) + d], p1 = offs[e*(NN+1) + d + 1];
  const int* el = elist + (long)e*EE;
  const u16* KVb = KV + (long)e*NN*512;

  float acc[8] = {0,0,0,0,0,0,0,0};
  float den = 0.f;

  auto process = [&](const uint4 kv){
    float f[8];
    f[0]=b2f((u16)(kv.x&0xffff)); f[1]=b2f((u16)(kv.x>>16));
    f[2]=b2f((u16)(kv.y&0xffff)); f[3]=b2f((u16)(kv.y>>16));
    f[4]=b2f((u16)(kv.z&0xffff)); f[5]=b2f((u16)(kv.z>>16));
    f[6]=b2f((u16)(kv.w&0xffff)); f[7]=b2f((u16)(kv.w>>16));
    float dp = q[0]*f[0]+q[1]*f[1]+q[2]*f[2]+q[3]*f[3]
             + q[4]*f[4]+q[5]*f[5]+q[6]*f[6]+q[7]*f[7];
    dp += __shfl_xor(dp,1); dp += __shfl_xor(dp,2);
    const float w = __expf(dp*scale);        // valid in lanes 0-31
    const float wv = __shfl(w, half);        // whole wave active: broadcast K-lane weight
    den += w;
    #pragma unroll
    for(int j=0;j<8;j++) acc[j] += wv*f[j];  // meaningful in lanes 32-63
  };

  int p = p0;
  for(; p+8 <= p1; p += 8){
    uint4 kv[8];
    #pragma unroll
    for(int u=0;u<8;u++) kv[u] = *(const uint4*)&KVb[(long)el[p+u]*512 + lane*8];
    #pragma unroll
    for(int u=0;u<8;u++) process(kv[u]);
  }
  for(; p+2 <= p1; p += 2){
    const uint4 a = *(const uint4*)&KVb[(long)el[p]*512 + lane*8];
    const uint4 b = *(const uint4*)&KVb[(long)el[p+1]*512 + lane*8];
    process(a); process(b);
  }
  if (p < p1){
    const uint4 a = *(const uint4*)&KVb[(long)el[p]*512 + lane*8];
    process(a);
  }

  // Broadcast denominator to V lanes while ALL lanes are active
  // (bpermute from an EXEC-masked lane is undefined — the round-5 NaN).
  const float denv = __shfl(den, half);

  if (lane >= 32){
    uint4 o = {0,0,0,0};
    if (p1 > p0){
      const float rden = 1.f/denv;
      o.x = pack2bf(acc[0]*rden, acc[1]*rden);
      o.y = pack2bf(acc[2]*rden, acc[3]*rden);
      o.z = pack2bf(acc[4]*rden, acc[5]*rden);
      o.w = pack2bf(acc[6]*rden, acc[7]*rden);
    }
    *(uint4*)&AGG[((long)dt*NN + d)*256 + half*8] = o;
  }
}

// ---------------- host ----------------
extern "C" void kernel_launch(void* const* d_in, const int* in_sizes, int n_in,
                              void* d_out, int out_size, void* d_ws, size_t ws_size,
                              hipStream_t stream) {
  const float* node_ft = (const float*)d_in[0];
  const float* scalars = (const float*)d_in[1];
  const int*   src_idx = (const int*)d_in[2];
  const int*   dst_idx = (const int*)d_in[3];
  const float* proj_w  = (const float*)d_in[4];
  const float* proj_b  = (const float*)d_in[5];
  const float* pv_ww   = (const float*)d_in[6];
  const float* pv_wb   = (const float*)d_in[7];
  const float* pv_lw   = (const float*)d_in[8];
  const float* pv_lb   = (const float*)d_in[9];
  const float* pv_sw   = (const float*)d_in[10];
  const float* pv_sb   = (const float*)d_in[11];
  const float* pv_gw   = (const float*)d_in[12];
  const float* pv_gb   = (const float*)d_in[13];
  const float* pv_fcw  = (const float*)d_in[14];
  const float* pv_fcb  = (const float*)d_in[15];
  const float* ima_w1  = (const float*)d_in[16];
  const float* ima_b1  = (const float*)d_in[17];
  const float* ima_w2  = (const float*)d_in[18];
  const float* lyr_k_w = (const float*)d_in[19];
  const float* lyr_q_w = (const float*)d_in[20];
  const float* lyr_v_w = (const float*)d_in[21];
  const float* lyr_fc_w= (const float*)d_in[22];
  const float* lyr_k_b = (const float*)d_in[23];
  const float* lyr_q_b = (const float*)d_in[24];
  const float* lyr_v_b = (const float*)d_in[25];
  const float* lyr_fc_b= (const float*)d_in[26];
  const float* lyr_att_w=(const float*)d_in[27];
  const float* lyr_val_w=(const float*)d_in[28];
  const float* lyr_canon=(const float*)d_in[29];
  const float* lyr_res = (const float*)d_in[30];
  const float* lyr_ln_g= (const float*)d_in[31];
  const float* lyr_ln_b= (const float*)d_in[32];
  const float* out_w   = (const float*)d_in[33];
  const float* out_b   = (const float*)d_in[34];
  const int*   sel     = (const int*)d_in[35];
  float* outp = (float*)d_out;

  char* ws = (char*)d_ws;
  size_t o = 0;
  auto alloc = [&](size_t bytes)->char*{ char* p = ws + o; o = (o + bytes + 255) & ~(size_t)255; return p; };

  int*   cnt    = (int*)  alloc(2*NN*4);
  int*   cur    = (int*)  alloc(2*NN*4);
  int*   offs   = (int*)  alloc(2*(NN+1)*4);
  int*   elist  = (int*)  alloc(2*EE*4);
  u16*   projwt = (u16*)  alloc((size_t)TT*128*256*2);
  u16*   fwt    = (u16*)  alloc((size_t)TT*6*1024*256*2);
  u16*   imaw1t = (u16*)  alloc((size_t)256*128*2);
  u16*   qkvwt  = (u16*)  alloc((size_t)3*262144*2);   // [K_eff | Q | V_eff]
  u16*   fcwt   = (u16*)  alloc((size_t)4*256*256*2);
  u16*   outwt  = (u16*)  alloc((size_t)64*256*2);
  float* hbuf   = (float*)alloc((size_t)TT*NN*256*4);
  float* wbuf   = (float*)alloc((size_t)TT*NN*7*4);
  float* ubuf   = (float*)alloc((size_t)12*256*4);
  float* vbuf   = (float*)alloc((size_t)12*256*4);
  float* qkvb   = (float*)alloc((size_t)TT*3*2*256*4); // [l][z][t][256]
  char*  arena  = alloc((size_t)176160768);
  if (o > ws_size) return;

  u16*   zbuf  = (u16*)arena;                         // (T,N,7,256) bf16, phase A
  u16*   Qb16  = (u16*)arena;                         // phase B (zbuf dead after ima_combine)
  u16*   KVb   = (u16*)(arena + 16777216);            // (T,N,512) bf16 interleaved K|V
  u16*   AGG16 = (u16*)(arena + 50331648);            // (T,N,256) bf16

  // ---- CSR build ----
  hipMemsetAsync(cnt, 0, 2*NN*4, stream);
  hipMemsetAsync(cur, 0, 2*NN*4, stream);
  csr_hist   <<<2*EE/256, 256, 0, stream>>>(dst_idx, cnt);
  csr_scan   <<<2, 256, 0, stream>>>(cnt, offs);
  csr_scatter<<<2*EE/256, 256, 0, stream>>>(dst_idx, src_idx, offs, cur, elist);

  // ---- weights prep ----
  tconv<<<dim3( 4,8, 2), dim3(32,8), 0, stream>>>(proj_w,   projwt, 128, 256);
  tconv<<<dim3(32,8,12), dim3(32,8), 0, stream>>>(pv_fcw,   fwt,   1024, 256);
  tconv<<<dim3( 8,4, 1), dim3(32,8), 0, stream>>>(ima_w1,   imaw1t, 256, 128);
  tconv<<<dim3( 8,8, 4), dim3(32,8), 0, stream>>>(lyr_q_w,  qkvwt + 262144, 256, 256);
  tconv<<<dim3( 8,8, 4), dim3(32,8), 0, stream>>>(lyr_fc_w, fcwt,   256, 256);
  tconv<<<dim3( 8,2, 1), dim3(32,8), 0, stream>>>(out_w,    outwt,  256, 64);
  eff_w<<<dim3(8,4,2), 256, 0, stream>>>(lyr_k_w, lyr_v_w, lyr_k_b, lyr_v_b,
                                         lyr_att_w, lyr_val_w, qkvwt, qkvb);
  pack_qb<<<4, 256, 0, stream>>>(lyr_q_b, qkvb);
  uv_k <<<12, 256, 0, stream>>>(pv_lw, pv_lb, pv_fcw, ubuf, vbuf);

  // ---- h0 = gelu(node_ft @ proj_w + b) -> zbuf slot 0 ----
  gemm_k<64,256,64,1,4,0,1,0><<<dim3(256,TT), 256, 0, stream>>>(
      node_ft, projwt, proj_b, zbuf, 128, 128, 1792,
      (long)NN*128, 32768L, 256L, (long)NN*1792, nullptr, nullptr, nullptr, nullptr,
      nullptr, nullptr);

  // ---- posvect -> zbuf slots 1..6 ----
  posvect_k<<<dim3(128,12), 256, 0, stream>>>(scalars, pv_ww, pv_wb,
      pv_sw, pv_sb, pv_gw, pv_gb, fwt, pv_fcb, ubuf, vbuf, zbuf);

  // ---- IMA gate fused epilogue, then softmax-combine ----
  gemm_k<64,128,64,2,2,1,4,0><<<dim3(3584,1), 256, 0, stream>>>(
      zbuf, imaw1t, ima_b1, wbuf, 256, 256, 0,
      0L, 0L, 0L, 0L, ima_w2, nullptr, nullptr, nullptr, nullptr, nullptr);
  ima_combine<<<TT*NN/4, 256, 0, stream>>>(zbuf, wbuf, hbuf);

  // ---- layers ----
  for (int l = 0; l < 2; ++l){
    // merged K/Q/V with folded head transforms: z=0 K->KVb[..0..255], z=1 Q->Qb16, z=2 V->KVb[..256..511]
    gemm_k<64,256,64,1,4,0,0,1><<<dim3(256,TT,3), 256, 0, stream>>>(
        hbuf, qkvwt + (size_t)l*131072, qkvb + (size_t)l*1536, Qb16, 256, 256, 256,
        (long)NN*256, 65536L, 256L, (long)NN*256, nullptr, nullptr, nullptr, KVb,
        nullptr, nullptr);

    attn_agg<<<dim3(NN/4, 2), 256, 0, stream>>>(Qb16, KVb, AGG16, offs, elist,
                                                lyr_canon + l*2*8);

    // fc + residual mix + LayerNorm fused, in-place on hbuf
    gemm_k<64,256,64,1,4,1,5,0><<<dim3(256,TT), 256, 0, stream>>>(
        AGG16, fcwt + (size_t)l*2*65536, lyr_fc_b + l*2*256, hbuf, 256, 256, 256,
        (long)NN*256, 65536L, 256L, (long)NN*256, hbuf, lyr_res + l*2, nullptr, nullptr,
        lyr_ln_g + l*2*256, lyr_ln_b + l*2*256);
  }

  // ---- out = h[sel] @ out_w + out_b ----
  gemm_k<256,64,64,4,1,0,0,0><<<dim3(64,1), 256, 0, stream>>>(
      hbuf, outwt, out_b, outp, 256, 256, 64,
      (long)NN*256, 0L, 0L, 0L, nullptr, nullptr, sel, nullptr, nullptr, nullptr);

  (void)in_sizes; (void)n_in; (void)out_size;
}

// Round 8
// 789.912 us; speedup vs baseline: 1.1953x; 1.1953x over previous
//
#include <hip/hip_runtime.h>
#include <hip/hip_bf16.h>

typedef unsigned short u16;
typedef unsigned int   u32;
typedef __attribute__((ext_vector_type(8))) short bf16x8;
typedef __attribute__((ext_vector_type(4))) float f32x4;
typedef __attribute__((ext_vector_type(4))) u16   u16x4;

constexpr int TT  = 2;
constexpr int NN  = 16384;
constexpr int EE  = 262144;

__device__ __forceinline__ u16 f2b(float f){
  u32 x = __float_as_uint(f);
  u32 r = (x + 0x7fffu + ((x >> 16) & 1u)) >> 16;
  return (u16)r;
}
__device__ __forceinline__ float b2f(u16 u){ return __uint_as_float(((u32)u) << 16); }
__device__ __forceinline__ u32 pack2bf(float a, float b){
  __hip_bfloat162 h = __float22bfloat162_rn(make_float2(a, b));
  union { __hip_bfloat162 h2; u32 u; } cv; cv.h2 = h; return cv.u;
}

// XOR-swizzled LDS addressing for stride-64 (u16) tiles: col c stored at
// c ^ ((row&7)*8). b128 fragment reads -> 2-way aliasing only (free, m136).
// R7 verified: SQ_LDS_BANK_CONFLICT == 0 with this layout.
__device__ __forceinline__ int swz64(int row, int c){
  return (row << 6) + (c ^ ((row & 7) << 3));
}

__device__ __forceinline__ float fast_tanh(float u){
  return 1.f - 2.f*__builtin_amdgcn_rcpf(1.f + __expf(2.f*u));
}
__device__ __forceinline__ float gelu_f(float x){
  float u = 0.7978845608028654f * (x + 0.044715f * x*x*x);
  return 0.5f * x * (1.f + fast_tanh(u));
}

// ---------------- CSR build ----------------
__global__ void csr_hist(const int* __restrict__ dst, int* __restrict__ cnt){
  int id = blockIdx.x*256 + threadIdx.x;
  int e = id >> 18;
  atomicAdd(&cnt[e*NN + dst[id]], 1);
}

__global__ void csr_scan(const int* __restrict__ cnt, int* __restrict__ offs){
  const int e = blockIdx.x, tid = threadIdx.x;
  const int CH = NN/256;
  const int* c = cnt + e*NN;
  int* of = offs + e*(NN+1);
  const int base = tid*CH;
  int s = 0;
  for(int i=0;i<CH;i++) s += c[base+i];
  __shared__ int sm[256];
  sm[tid] = s; __syncthreads();
  for(int o=1;o<256;o<<=1){
    int v = (tid>=o) ? sm[tid-o] : 0;
    __syncthreads();
    sm[tid] += v;
    __syncthreads();
  }
  int run = sm[tid] - s;
  for(int i=0;i<CH;i++){ of[base+i] = run; run += c[base+i]; }
  if(tid==255) of[NN] = run;
}

__global__ void csr_scatter(const int* __restrict__ dst, const int* __restrict__ src,
                            const int* __restrict__ offs, int* __restrict__ cur,
                            int* __restrict__ elist){
  int id = blockIdx.x*256 + threadIdx.x;
  int e = id >> 18;
  int d = dst[id];
  int pos = offs[e*(NN+1)+d] + atomicAdd(&cur[e*NN+d], 1);
  elist[e*EE + pos] = src[id];
}

// ---------------- transpose + bf16 convert (weights) ----------------
__global__ void tconv(const float* __restrict__ in, u16* __restrict__ out, int K, int Nc){
  __shared__ float tile[32][33];
  const long base = (long)blockIdx.z * K * Nc;
  const int k0 = blockIdx.x*32, n0 = blockIdx.y*32;
  const int tx = threadIdx.x, ty = threadIdx.y;
  for(int i=0;i<32;i+=8)
    tile[ty+i][tx] = in[base + (long)(k0+ty+i)*Nc + n0+tx];
  __syncthreads();
  for(int i=0;i<32;i+=8)
    out[base + (long)(n0+ty+i)*K + k0+tx] = f2b(tile[tx][ty+i]);
}

// ---------------- fold head transforms into K/V weights ----------------
__global__ void eff_w(const float* __restrict__ kw, const float* __restrict__ vw,
                      const float* __restrict__ kb, const float* __restrict__ vb,
                      const float* __restrict__ att, const float* __restrict__ val,
                      u16* __restrict__ qkvwt, float* __restrict__ qkvb){
  const int h = blockIdx.x, lt = blockIdx.y, kv = blockIdx.z;   // 8 x 4 x 2
  const int l = lt >> 1;
  const float* W = (kv ? vw : kw) + (long)lt*65536;
  const float* A = (kv ? val : att) + (long)lt*8192 + h*1024;
  const float* B = (kv ? vb : kb) + (long)lt*256 + h*32;
  __shared__ float As[32][33];
  for(int idx=threadIdx.x; idx<1024; idx+=256) As[idx>>5][idx&31] = A[idx];
  __syncthreads();
  const int r = threadIdx.x;
  float x[32];
  const float* wr = W + (long)r*256 + h*32;
  #pragma unroll
  for(int i=0;i<32;i++) x[i] = wr[i];
  u16* outb = qkvwt + (kv ? 524288 : 0) + (long)lt*65536;
  #pragma unroll 4
  for(int j=0;j<32;j++){
    float s = 0.f;
    #pragma unroll
    for(int i=0;i<32;i++) s = fmaf(x[i], As[i][j], s);
    outb[(h*32 + j)*256 + r] = f2b(s);
  }
  if (r < 32){
    float s = 0.f;
    #pragma unroll
    for(int i=0;i<32;i++) s = fmaf(B[i], As[i][r], s);
    qkvb[l*1536 + (kv ? 1024 : 0) + (lt&1)*256 + h*32 + r] = s;
  }
}

__global__ void pack_qb(const float* __restrict__ qb, float* __restrict__ qkvb){
  int i = blockIdx.x*256 + threadIdx.x;   // 1024 = L*T*256
  int l = i >> 9, r = i & 511;
  qkvb[l*1536 + 512 + r] = qb[l*512 + r];
}

// ---------------- rank-1 precompute for the linear posvect block ----------------
__global__ void uv_k(const float* __restrict__ lw, const float* __restrict__ lb,
                     const float* __restrict__ fcw,
                     float* __restrict__ ubuf, float* __restrict__ vbuf){
  const int by = blockIdx.x;            // 12
  const int j  = threadIdx.x;           // 256
  const float* fw = fcw + ((long)by*1024 + 256)*256 + j;
  const float* lwp = lw + by*256;
  const float* lbp = lb + by*256;
  float u = 0.f, v = 0.f;
  for(int h=0; h<256; h++){
    const float f = fw[(long)h*256];
    u = fmaf(lwp[h], f, u);
    v = fmaf(lbp[h], f, v);
  }
  ubuf[by*256+j] = u; vbuf[by*256+j] = v;
}

// ---------------- generic bf16-MFMA GEMM (XOR-swizzled LDS, 40KB) ----------------
// EPI: 0 = fp32 +bias; 1 = gelu->bf16; 4 = tanh dot w2 row-sum; 5 = residual mix + LayerNorm
// ASRC: 0 = fp32 A; 1 = bf16 A.  ZQKV: blockIdx.z = {K,Q,V}; K/V -> bf16 KV record, Q -> bf16.
// launch_bounds(256,2): VGPR cap 256 — unified VGPR+AGPR must hold the MFMA
// accumulators; (256,3+) caps below that and SPILLS them to scratch (R7: 674 MB
// scratch writes, 2.5x regression). Do not raise.
template<int BM,int BN,int BK,int WM,int WN,int ASRC,int EPI,int ZQKV>
__global__ void __launch_bounds__(256,2)
gemm_k(const void* __restrict__ Av, const u16* __restrict__ Bt,
       const float* __restrict__ bias, void* Cv,
       int K, int lda, int ldc,
       long strideA, long strideB, long strideBias, long strideC,
       const float* resid, const float* __restrict__ resgate,
       const int* __restrict__ selp, u16* __restrict__ kvout,
       const float* __restrict__ lng, const float* __restrict__ lnb)
{
  static_assert(BK == 64, "swizzle assumes BK=64");
  constexpr int WTM = BM/WM, WTN = BN/WN;
  constexpr int RM = WTM/16, RN = WTN/16;
  __shared__ u16 lA[BM*64];
  __shared__ u16 lB[BN*64];

  const int tid = threadIdx.x;
  const int by  = blockIdx.y;
  const int m0  = blockIdx.x * BM;
  const int lane = tid & 63, wvi = tid >> 6;
  const int wr = wvi / WN, wc = wvi % WN;
  const int wr0 = wr * WTM, wc0 = wc * WTN;
  const int l16 = lane & 15, qd = lane >> 4;

  int zq = 0; int boff = 0;
  if constexpr (ZQKV){
    zq = blockIdx.z;
    boff = zq*512;
  }

  long aoff = (long)by * strideA;
  if (selp) aoff += (long)selp[0] * strideA;
  const float* A32 = (const float*)Av;
  const u16*   A16 = (const u16*)Av;
  const u16*   Bp  = Bt + (long)by * strideB + (long)zq * 262144;

  f32x4 acc[RM][RN];
  #pragma unroll
  for(int i=0;i<RM;i++)
    #pragma unroll
    for(int j=0;j<RN;j++) acc[i][j] = (f32x4){0.f,0.f,0.f,0.f};

  for(int k0=0;k0<K;k0+=BK){
    if constexpr (ASRC == 0){
      for(int idx=tid; idx < BM*16; idx += 256){
        int r = idx >> 4, c = (idx & 15)*4;
        const float4 v = *(const float4*)(A32 + aoff + (long)(m0+r)*lda + k0 + c);
        uint2 o2; o2.x = pack2bf(v.x, v.y); o2.y = pack2bf(v.z, v.w);
        *(uint2*)&lA[swz64(r, c)] = o2;
      }
    } else {
      for(int idx=tid; idx < BM*8; idx += 256){
        int r = idx >> 3, c = (idx & 7)*8;
        *(uint4*)&lA[swz64(r, c)] = *(const uint4*)(A16 + aoff + (long)(m0+r)*lda + k0 + c);
      }
    }
    for(int idx=tid; idx < BN*8; idx += 256){
      int n = idx >> 3, c = (idx & 7)*8;
      *(uint4*)&lB[swz64(n, c)] = *(const uint4*)(Bp + (long)n*K + k0 + c);
    }
    __syncthreads();
    #pragma unroll
    for(int ks=0; ks<BK; ks+=32){
      bf16x8 af[RM], bfr[RN];
      #pragma unroll
      for(int i=0;i<RM;i++) af[i]  = *(const bf16x8*)&lA[swz64(wr0 + i*16 + l16, ks + qd*8)];
      #pragma unroll
      for(int j=0;j<RN;j++) bfr[j] = *(const bf16x8*)&lB[swz64(wc0 + j*16 + l16, ks + qd*8)];
      #pragma unroll
      for(int i=0;i<RM;i++)
        #pragma unroll
        for(int j=0;j<RN;j++)
          acc[i][j] = __builtin_amdgcn_mfma_f32_16x16x32_bf16(af[i], bfr[j], acc[i][j], 0,0,0);
    }
    __syncthreads();
  }

  if constexpr (EPI == 4){
    float* rsum = (float*)lA;   // alias dead A-tile (post-barrier safe)
    #pragma unroll
    for(int i=0;i<RM;i++){
      #pragma unroll
      for(int r=0;r<4;r++){
        float part = 0.f;
        #pragma unroll
        for(int jj=0;jj<RN;jj++){
          const int col = wc0 + jj*16 + l16;
          const float v = fast_tanh(acc[i][jj][r] + bias[boff + col]);
          part += v * resid[col];
        }
        part += __shfl_xor(part,1); part += __shfl_xor(part,2);
        part += __shfl_xor(part,4); part += __shfl_xor(part,8);
        if (l16 == 0) rsum[wc*BM + wr0 + i*16 + qd*4 + r] = part;
      }
    }
    __syncthreads();
    if (tid < BM){
      float s = 0.f;
      #pragma unroll
      for(int w=0;w<WN;w++) s += rsum[w*BM + tid];
      ((float*)Cv)[m0 + tid] = s;
    }
    return;
  } else if constexpr (EPI == 5){
    // residual mix -> LayerNorm fused; Cv == resid buffer (in-place per-row; barrier-separated)
    float* red1 = (float*)lA;            // WN*BM
    float* red2 = red1 + WN*BM;          // WN*BM
    float* muv  = red2 + WN*BM;          // BM*2
    const float alpha = 1.f/(1.f + __expf(-resgate[by]));
    #pragma unroll
    for(int i=0;i<RM;i++){
      #pragma unroll
      for(int r=0;r<4;r++){
        const int rloc = wr0 + i*16 + qd*4 + r;
        const int row = m0 + rloc;
        float s1 = 0.f, s2 = 0.f;
        #pragma unroll
        for(int j=0;j<RN;j++){
          const int col = wc0 + j*16 + l16;
          float v = acc[i][j][r] + bias[(long)by*strideBias + col];
          const float hv = resid[(long)by*strideC + (long)row*ldc + col];
          v = v*alpha + hv*(1.f - alpha);
          acc[i][j][r] = v;
          s1 += v; s2 += v*v;
        }
        s1 += __shfl_xor(s1,1); s1 += __shfl_xor(s1,2); s1 += __shfl_xor(s1,4); s1 += __shfl_xor(s1,8);
        s2 += __shfl_xor(s2,1); s2 += __shfl_xor(s2,2); s2 += __shfl_xor(s2,4); s2 += __shfl_xor(s2,8);
        if (l16 == 0){ red1[wc*BM + rloc] = s1; red2[wc*BM + rloc] = s2; }
      }
    }
    __syncthreads();
    if (tid < BM){
      float s1 = 0.f, s2 = 0.f;
      #pragma unroll
      for(int w=0;w<WN;w++){ s1 += red1[w*BM + tid]; s2 += red2[w*BM + tid]; }
      const float mu = s1*(1.f/256.f);
      const float var = s2*(1.f/256.f) - mu*mu;
      muv[tid*2]   = mu;
      muv[tid*2+1] = rsqrtf(fmaxf(var, 0.f) + 1e-5f);
    }
    __syncthreads();
    #pragma unroll
    for(int i=0;i<RM;i++){
      #pragma unroll
      for(int r=0;r<4;r++){
        const int rloc = wr0 + i*16 + qd*4 + r;
        const int row = m0 + rloc;
        const float mu = muv[rloc*2], rs = muv[rloc*2+1];
        #pragma unroll
        for(int j=0;j<RN;j++){
          const int col = wc0 + j*16 + l16;
          const float o = (acc[i][j][r]-mu)*rs*lng[by*256+col] + lnb[by*256+col];
          ((float*)Cv)[(long)by*strideC + (long)row*ldc + col] = o;
        }
      }
    }
    return;
  } else {
    #pragma unroll
    for(int i=0;i<RM;i++){
      #pragma unroll
      for(int j=0;j<RN;j++){
        const int col = wc0 + j*16 + l16;
        const float bv = bias[(long)by*strideBias + boff + col];
        #pragma unroll
        for(int r=0;r<4;r++){
          const int row = m0 + wr0 + i*16 + qd*4 + r;
          float v = acc[i][j][r] + bv;
          if constexpr (ZQKV){
            if (zq == 1)
              ((u16*)Cv)[(long)by*strideC + (long)row*ldc + col] = f2b(v);   // Q bf16
            else
              kvout[((long)by*NN + row)*512 + (zq==2 ? 256 : 0) + col] = f2b(v);
          } else {
            const long cidx = (long)by*strideC + (long)row*ldc + col;
            if constexpr (EPI == 0) ((float*)Cv)[cidx] = v;
            else ((u16*)Cv)[cidx] = f2b(gelu_f(v));
          }
        }
      }
    }
  }
}

// ---------------- posvect: K=768, swizzled LDS; launch_bounds(256,2) ------------
// acc[8][4] = 128 accumulator regs: any tighter occupancy bound spills (R7).
__global__ void __launch_bounds__(256,2)
posvect_k(const float* __restrict__ scalars,
          const float* __restrict__ ww, const float* __restrict__ wb,
          const float* __restrict__ sw, const float* __restrict__ sb,
          const float* __restrict__ gw, const float* __restrict__ gb,
          const u16* __restrict__ fwt, const float* __restrict__ fcb,
          const float* __restrict__ ubuf, const float* __restrict__ vbuf,
          u16* __restrict__ zb)
{
  __shared__ u16 lA[128*64];
  __shared__ u16 lB[256*64];
  __shared__ float xs[128];
  const int tid = threadIdx.x;
  const int by = blockIdx.y;
  const int t = by / 6, m = by % 6;
  const int m0 = blockIdx.x * 128;
  const int lane = tid & 63, wvi = tid >> 6;
  const int wc0 = wvi * 64;
  const int l16 = lane & 15, qd = lane >> 4;
  const int pofs = by * 256;

  if (tid < 128) xs[tid] = scalars[((long)t*NN + m0 + tid)*6 + m];

  const u16* Bp = fwt + (long)by * (1024*256);

  f32x4 acc[8][4];
  #pragma unroll
  for(int i=0;i<8;i++)
    #pragma unroll
    for(int j=0;j<4;j++) acc[i][j] = (f32x4){0.f,0.f,0.f,0.f};

  __syncthreads();

  const int jg   = tid & 7;
  const int row0 = tid >> 3;

  for(int kt=0; kt<12; kt++){
    const int k0 = kt*64 + (kt>=4 ? 256 : 0);        // skip the linear slab
    const int ia = (kt<4) ? 0 : ((kt<8) ? 2 : 3);
    const int hh = (k0 & 255) + jg*8;
    const float* wsel = ((ia==0)?ww:(ia==2)?sw:gw) + pofs;
    const float* bsel = ((ia==0)?wb:(ia==2)?sb:gb) + pofs;
    const float4 wa  = *(const float4*)(wsel + hh);
    const float4 wv2 = *(const float4*)(wsel + hh + 4);
    const float4 ba  = *(const float4*)(bsel + hh);
    const float4 bv2 = *(const float4*)(bsel + hh + 4);
    #pragma unroll
    for(int it=0; it<4; it++){
      const int row = row0 + it*32;
      const float x = xs[row];
      float y[8];
      y[0]=fmaf(x,wa.x,ba.x);   y[1]=fmaf(x,wa.y,ba.y);
      y[2]=fmaf(x,wa.z,ba.z);   y[3]=fmaf(x,wa.w,ba.w);
      y[4]=fmaf(x,wv2.x,bv2.x); y[5]=fmaf(x,wv2.y,bv2.y);
      y[6]=fmaf(x,wv2.z,bv2.z); y[7]=fmaf(x,wv2.w,bv2.w);
      float a[8];
      if (ia==0){
        #pragma unroll
        for(int i=0;i<8;i++) a[i] = __sinf(y[i]);
      } else if (ia==2){
        #pragma unroll
        for(int i=0;i<8;i++){
          const float ab = fabsf(y[i]);
          a[i] = fmaxf(y[i],0.f) + __logf(1.f + __expf(-ab));
        }
      } else {
        #pragma unroll
        for(int i=0;i<8;i++)
          a[i] = __builtin_amdgcn_rcpf(1.f + __expf(-y[i]));
      }
      uint4 pv;
      pv.x = pack2bf(a[0],a[1]); pv.y = pack2bf(a[2],a[3]);
      pv.z = pack2bf(a[4],a[5]); pv.w = pack2bf(a[6],a[7]);
      *(uint4*)&lA[swz64(row, jg*8)] = pv;
    }
    for(int idx=tid; idx<2048; idx+=256){
      int n = idx >> 3, c = (idx & 7)*8;
      *(uint4*)&lB[swz64(n, c)] = *(const uint4*)(Bp + (long)n*1024 + k0 + c);
    }
    __syncthreads();
    #pragma unroll
    for(int ks=0; ks<64; ks+=32){
      bf16x8 af[8], bfr[4];
      #pragma unroll
      for(int i=0;i<8;i++) af[i]  = *(const bf16x8*)&lA[swz64(i*16 + l16, ks + qd*8)];
      #pragma unroll
      for(int jj=0;jj<4;jj++) bfr[jj] = *(const bf16x8*)&lB[swz64(wc0 + jj*16 + l16, ks + qd*8)];
      #pragma unroll
      for(int i=0;i<8;i++)
        #pragma unroll
        for(int jj=0;jj<4;jj++)
          acc[i][jj] = __builtin_amdgcn_mfma_f32_16x16x32_bf16(af[i], bfr[jj], acc[i][jj], 0,0,0);
    }
    __syncthreads();
  }

  #pragma unroll
  for(int i=0;i<8;i++){
    #pragma unroll
    for(int jj=0;jj<4;jj++){
      const int col = wc0 + jj*16 + l16;
      const float bv = fcb[pofs + col] + vbuf[pofs + col];
      const float uu = ubuf[pofs + col];
      #pragma unroll
      for(int r=0;r<4;r++){
        const int row = i*16 + qd*4 + r;
        const float v = acc[i][jj][r] + bv + xs[row]*uu;
        zb[((long)t*NN + m0 + row)*1792 + (m+1)*256 + col] = f2b(gelu_f(v));
      }
    }
  }
}

// ---------------- IMA combine ----------------
__global__ void ima_combine(const u16* __restrict__ zb, const float* __restrict__ wbuf,
                            float* __restrict__ H){
  const int row = blockIdx.x*4 + (threadIdx.x>>6);
  const int lane = threadIdx.x & 63;
  const float* w7 = wbuf + (long)row*7;
  float w[7]; float mx = -1e30f;
  #pragma unroll
  for(int m=0;m<7;m++){ w[m] = w7[m]; mx = fmaxf(mx, w[m]); }
  float sum = 0.f;
  #pragma unroll
  for(int m=0;m<7;m++){ w[m] = __expf(w[m]-mx); sum += w[m]; }
  const float inv = __builtin_amdgcn_rcpf(sum);
  float4 acc = {0,0,0,0};
  #pragma unroll
  for(int m=0;m<7;m++){
    const u16x4 z4 = *(const u16x4*)&zb[((long)row*7 + m)*256 + lane*4];
    const float p = w[m]*inv;
    acc.x += p*b2f(z4.x); acc.y += p*b2f(z4.y); acc.z += p*b2f(z4.z); acc.w += p*b2f(z4.w);
  }
  *(float4*)&H[(long)row*256 + lane*4] = acc;
}

// ---------------- attention aggregation: split-lane KV gather, unroll-8 ----------
// lanes 0-31: K dims half*8..+7 (head = half>>2); lanes 32-63: V dims half*8..+7.
__global__ void attn_agg(const u16* __restrict__ Q16, const u16* __restrict__ KV,
                         u16* __restrict__ AGG,
                         const int* __restrict__ offs, const int* __restrict__ elist,
                         const float* __restrict__ canon){
  const int e = blockIdx.y, dt = 1 - e;
  const int d = blockIdx.x*4 + (threadIdx.x>>6);
  const int lane = threadIdx.x & 63;
  const int half = lane & 31;
  const float scale = canon[e*8 + (half>>2)] * 0.17677669529663687f;

  const uint4 qv = *(const uint4*)&Q16[((long)dt*NN + d)*256 + half*8];
  float q[8];
  q[0]=b2f((u16)(qv.x&0xffff)); q[1]=b2f((u16)(qv.x>>16));
  q[2]=b2f((u16)(qv.y&0xffff)); q[3]=b2f((u16)(qv.y>>16));
  q[4]=b2f((u16)(qv.z&0xffff)); q[5]=b2f((u16)(qv.z>>16));
  q[6]=b2f((u16)(qv.w&0xffff)); q[7]=b2f((u16)(qv.w>>16));

  const int p0 = offs[e*(NN+1) + d], p1 = offs[e*(NN+1) + d + 1];
  const int* el = elist + (long)e*EE;
  const u16* KVb = KV + (long)e*NN*512;

  float acc[8] = {0,0,0,0,0,0,0,0};
  float den = 0.f;

  auto process = [&](const uint4 kv){
    float f[8];
    f[0]=b2f((u16)(kv.x&0xffff)); f[1]=b2f((u16)(kv.x>>16));
    f[2]=b2f((u16)(kv.y&0xffff)); f[3]=b2f((u16)(kv.y>>16));
    f[4]=b2f((u16)(kv.z&0xffff)); f[5]=b2f((u16)(kv.z>>16));
    f[6]=b2f((u16)(kv.w&0xffff)); f[7]=b2f((u16)(kv.w>>16));
    float dp = q[0]*f[0]+q[1]*f[1]+q[2]*f[2]+q[3]*f[3]
             + q[4]*f[4]+q[5]*f[5]+q[6]*f[6]+q[7]*f[7];
    dp += __shfl_xor(dp,1); dp += __shfl_xor(dp,2);
    const float w = __expf(dp*scale);        // valid in lanes 0-31
    const float wv = __shfl(w, half);        // whole wave active: broadcast K-lane weight
    den += w;
    #pragma unroll
    for(int j=0;j<8;j++) acc[j] += wv*f[j];  // meaningful in lanes 32-63
  };

  int p = p0;
  for(; p+8 <= p1; p += 8){
    uint4 kv[8];
    #pragma unroll
    for(int u=0;u<8;u++) kv[u] = *(const uint4*)&KVb[(long)el[p+u]*512 + lane*8];
    #pragma unroll
    for(int u=0;u<8;u++) process(kv[u]);
  }
  for(; p+2 <= p1; p += 2){
    const uint4 a = *(const uint4*)&KVb[(long)el[p]*512 + lane*8];
    const uint4 b = *(const uint4*)&KVb[(long)el[p+1]*512 + lane*8];
    process(a); process(b);
  }
  if (p < p1){
    const uint4 a = *(const uint4*)&KVb[(long)el[p]*512 + lane*8];
    process(a);
  }

  // Broadcast denominator to V lanes while ALL lanes are active
  // (bpermute from an EXEC-masked lane is undefined — the round-5 NaN).
  const float denv = __shfl(den, half);

  if (lane >= 32){
    uint4 o = {0,0,0,0};
    if (p1 > p0){
      const float rden = 1.f/denv;
      o.x = pack2bf(acc[0]*rden, acc[1]*rden);
      o.y = pack2bf(acc[2]*rden, acc[3]*rden);
      o.z = pack2bf(acc[4]*rden, acc[5]*rden);
      o.w = pack2bf(acc[6]*rden, acc[7]*rden);
    }
    *(uint4*)&AGG[((long)dt*NN + d)*256 + half*8] = o;
  }
}

// ---------------- host ----------------
extern "C" void kernel_launch(void* const* d_in, const int* in_sizes, int n_in,
                              void* d_out, int out_size, void* d_ws, size_t ws_size,
                              hipStream_t stream) {
  const float* node_ft = (const float*)d_in[0];
  const float* scalars = (const float*)d_in[1];
  const int*   src_idx = (const int*)d_in[2];
  const int*   dst_idx = (const int*)d_in[3];
  const float* proj_w  = (const float*)d_in[4];
  const float* proj_b  = (const float*)d_in[5];
  const float* pv_ww   = (const float*)d_in[6];
  const float* pv_wb   = (const float*)d_in[7];
  const float* pv_lw   = (const float*)d_in[8];
  const float* pv_lb   = (const float*)d_in[9];
  const float* pv_sw   = (const float*)d_in[10];
  const float* pv_sb   = (const float*)d_in[11];
  const float* pv_gw   = (const float*)d_in[12];
  const float* pv_gb   = (const float*)d_in[13];
  const float* pv_fcw  = (const float*)d_in[14];
  const float* pv_fcb  = (const float*)d_in[15];
  const float* ima_w1  = (const float*)d_in[16];
  const float* ima_b1  = (const float*)d_in[17];
  const float* ima_w2  = (const float*)d_in[18];
  const float* lyr_k_w = (const float*)d_in[19];
  const float* lyr_q_w = (const float*)d_in[20];
  const float* lyr_v_w = (const float*)d_in[21];
  const float* lyr_fc_w= (const float*)d_in[22];
  const float* lyr_k_b = (const float*)d_in[23];
  const float* lyr_q_b = (const float*)d_in[24];
  const float* lyr_v_b = (const float*)d_in[25];
  const float* lyr_fc_b= (const float*)d_in[26];
  const float* lyr_att_w=(const float*)d_in[27];
  const float* lyr_val_w=(const float*)d_in[28];
  const float* lyr_canon=(const float*)d_in[29];
  const float* lyr_res = (const float*)d_in[30];
  const float* lyr_ln_g= (const float*)d_in[31];
  const float* lyr_ln_b= (const float*)d_in[32];
  const float* out_w   = (const float*)d_in[33];
  const float* out_b   = (const float*)d_in[34];
  const int*   sel     = (const int*)d_in[35];
  float* outp = (float*)d_out;

  char* ws = (char*)d_ws;
  size_t o = 0;
  auto alloc = [&](size_t bytes)->char*{ char* p = ws + o; o = (o + bytes + 255) & ~(size_t)255; return p; };

  int*   cnt    = (int*)  alloc(2*NN*4);
  int*   cur    = (int*)  alloc(2*NN*4);
  int*   offs   = (int*)  alloc(2*(NN+1)*4);
  int*   elist  = (int*)  alloc(2*EE*4);
  u16*   projwt = (u16*)  alloc((size_t)TT*128*256*2);
  u16*   fwt    = (u16*)  alloc((size_t)TT*6*1024*256*2);
  u16*   imaw1t = (u16*)  alloc((size_t)256*128*2);
  u16*   qkvwt  = (u16*)  alloc((size_t)3*262144*2);   // [K_eff | Q | V_eff]
  u16*   fcwt   = (u16*)  alloc((size_t)4*256*256*2);
  u16*   outwt  = (u16*)  alloc((size_t)64*256*2);
  float* hbuf   = (float*)alloc((size_t)TT*NN*256*4);
  float* wbuf   = (float*)alloc((size_t)TT*NN*7*4);
  float* ubuf   = (float*)alloc((size_t)12*256*4);
  float* vbuf   = (float*)alloc((size_t)12*256*4);
  float* qkvb   = (float*)alloc((size_t)TT*3*2*256*4); // [l][z][t][256]
  char*  arena  = alloc((size_t)176160768);
  if (o > ws_size) return;

  u16*   zbuf  = (u16*)arena;                         // (T,N,7,256) bf16, phase A
  u16*   Qb16  = (u16*)arena;                         // phase B (zbuf dead after ima_combine)
  u16*   KVb   = (u16*)(arena + 16777216);            // (T,N,512) bf16 interleaved K|V
  u16*   AGG16 = (u16*)(arena + 50331648);            // (T,N,256) bf16

  // ---- CSR build ----
  hipMemsetAsync(cnt, 0, 2*NN*4, stream);
  hipMemsetAsync(cur, 0, 2*NN*4, stream);
  csr_hist   <<<2*EE/256, 256, 0, stream>>>(dst_idx, cnt);
  csr_scan   <<<2, 256, 0, stream>>>(cnt, offs);
  csr_scatter<<<2*EE/256, 256, 0, stream>>>(dst_idx, src_idx, offs, cur, elist);

  // ---- weights prep ----
  tconv<<<dim3( 4,8, 2), dim3(32,8), 0, stream>>>(proj_w,   projwt, 128, 256);
  tconv<<<dim3(32,8,12), dim3(32,8), 0, stream>>>(pv_fcw,   fwt,   1024, 256);
  tconv<<<dim3( 8,4, 1), dim3(32,8), 0, stream>>>(ima_w1,   imaw1t, 256, 128);
  tconv<<<dim3( 8,8, 4), dim3(32,8), 0, stream>>>(lyr_q_w,  qkvwt + 262144, 256, 256);
  tconv<<<dim3( 8,8, 4), dim3(32,8), 0, stream>>>(lyr_fc_w, fcwt,   256, 256);
  tconv<<<dim3( 8,2, 1), dim3(32,8), 0, stream>>>(out_w,    outwt,  256, 64);
  eff_w<<<dim3(8,4,2), 256, 0, stream>>>(lyr_k_w, lyr_v_w, lyr_k_b, lyr_v_b,
                                         lyr_att_w, lyr_val_w, qkvwt, qkvb);
  pack_qb<<<4, 256, 0, stream>>>(lyr_q_b, qkvb);
  uv_k <<<12, 256, 0, stream>>>(pv_lw, pv_lb, pv_fcw, ubuf, vbuf);

  // ---- h0 = gelu(node_ft @ proj_w + b) -> zbuf slot 0 ----
  gemm_k<64,256,64,1,4,0,1,0><<<dim3(256,TT), 256, 0, stream>>>(
      node_ft, projwt, proj_b, zbuf, 128, 128, 1792,
      (long)NN*128, 32768L, 256L, (long)NN*1792, nullptr, nullptr, nullptr, nullptr,
      nullptr, nullptr);

  // ---- posvect -> zbuf slots 1..6 ----
  posvect_k<<<dim3(128,12), 256, 0, stream>>>(scalars, pv_ww, pv_wb,
      pv_sw, pv_sb, pv_gw, pv_gb, fwt, pv_fcb, ubuf, vbuf, zbuf);

  // ---- IMA gate fused epilogue, then softmax-combine ----
  gemm_k<64,128,64,2,2,1,4,0><<<dim3(3584,1), 256, 0, stream>>>(
      zbuf, imaw1t, ima_b1, wbuf, 256, 256, 0,
      0L, 0L, 0L, 0L, ima_w2, nullptr, nullptr, nullptr, nullptr, nullptr);
  ima_combine<<<TT*NN/4, 256, 0, stream>>>(zbuf, wbuf, hbuf);

  // ---- layers ----
  for (int l = 0; l < 2; ++l){
    // merged K/Q/V with folded head transforms: z=0 K->KVb[..0..255], z=1 Q->Qb16, z=2 V->KVb[..256..511]
    gemm_k<64,256,64,1,4,0,0,1><<<dim3(256,TT,3), 256, 0, stream>>>(
        hbuf, qkvwt + (size_t)l*131072, qkvb + (size_t)l*1536, Qb16, 256, 256, 256,
        (long)NN*256, 65536L, 256L, (long)NN*256, nullptr, nullptr, nullptr, KVb,
        nullptr, nullptr);

    attn_agg<<<dim3(NN/4, 2), 256, 0, stream>>>(Qb16, KVb, AGG16, offs, elist,
                                                lyr_canon + l*2*8);

    // fc + residual mix + LayerNorm fused, in-place on hbuf
    gemm_k<64,256,64,1,4,1,5,0><<<dim3(256,TT), 256, 0, stream>>>(
        AGG16, fcwt + (size_t)l*2*65536, lyr_fc_b + l*2*256, hbuf, 256, 256, 256,
        (long)NN*256, 65536L, 256L, (long)NN*256, hbuf, lyr_res + l*2, nullptr, nullptr,
        lyr_ln_g + l*2*256, lyr_ln_b + l*2*256);
  }

  // ---- out = h[sel] @ out_w + out_b ----
  gemm_k<256,64,64,4,1,0,0,0><<<dim3(64,1), 256, 0, stream>>>(
      hbuf, outwt, out_b, outp, 256, 256, 64,
      (long)NN*256, 0L, 0L, 0L, nullptr, nullptr, sel, nullptr, nullptr, nullptr);

  (void)in_sizes; (void)n_in; (void)out_size;
}

// Round 9
// 739.063 us; speedup vs baseline: 1.2775x; 1.0688x over previous
//
#include <hip/hip_runtime.h>
#include <hip/hip_bf16.h>

typedef unsigned short u16;
typedef unsigned int   u32;
typedef __attribute__((ext_vector_type(8))) short bf16x8;
typedef __attribute__((ext_vector_type(4))) float f32x4;
typedef __attribute__((ext_vector_type(4))) u16   u16x4;

constexpr int TT  = 2;
constexpr int NN  = 16384;
constexpr int EE  = 262144;

__device__ __forceinline__ u16 f2b(float f){
  u32 x = __float_as_uint(f);
  u32 r = (x + 0x7fffu + ((x >> 16) & 1u)) >> 16;
  return (u16)r;
}
__device__ __forceinline__ float b2f(u16 u){ return __uint_as_float(((u32)u) << 16); }
__device__ __forceinline__ u32 pack2bf(float a, float b){
  __hip_bfloat162 h = __float22bfloat162_rn(make_float2(a, b));
  union { __hip_bfloat162 h2; u32 u; } cv; cv.h2 = h; return cv.u;
}

// XOR-swizzled LDS addressing for stride-64 (u16) tiles: col c stored at
// c ^ ((row&7)*8). b128 fragment reads -> 2-way aliasing only (free, m136).
// R7/R8 verified: SQ_LDS_BANK_CONFLICT == 0 with this layout.
__device__ __forceinline__ int swz64(int row, int c){
  return (row << 6) + (c ^ ((row & 7) << 3));
}

// Async global->LDS, 16B per lane, wave-uniform LDS base (HW: base + lane*16).
// With 8 rows per 1KB chunk, row&7 == lane>>3, so the swizzle is applied by
// permuting the SOURCE column per lane (coalescing preserved: 8 lanes still
// cover one 128B segment per row).
__device__ __forceinline__ void gl_lds16(const u16* g, u16* l){
  __builtin_amdgcn_global_load_lds(
      (const __attribute__((address_space(1))) u32*)g,
      (__attribute__((address_space(3))) u32*)l, 16, 0, 0);
}

__device__ __forceinline__ float fast_tanh(float u){
  return 1.f - 2.f*__builtin_amdgcn_rcpf(1.f + __expf(2.f*u));
}
__device__ __forceinline__ float gelu_f(float x){
  float u = 0.7978845608028654f * (x + 0.044715f * x*x*x);
  return 0.5f * x * (1.f + fast_tanh(u));
}

// ---------------- CSR build ----------------
__global__ void csr_hist(const int* __restrict__ dst, int* __restrict__ cnt){
  int id = blockIdx.x*256 + threadIdx.x;
  int e = id >> 18;
  atomicAdd(&cnt[e*NN + dst[id]], 1);
}

__global__ void csr_scan(const int* __restrict__ cnt, int* __restrict__ offs){
  const int e = blockIdx.x, tid = threadIdx.x;
  const int CH = NN/256;
  const int* c = cnt + e*NN;
  int* of = offs + e*(NN+1);
  const int base = tid*CH;
  int s = 0;
  for(int i=0;i<CH;i++) s += c[base+i];
  __shared__ int sm[256];
  sm[tid] = s; __syncthreads();
  for(int o=1;o<256;o<<=1){
    int v = (tid>=o) ? sm[tid-o] : 0;
    __syncthreads();
    sm[tid] += v;
    __syncthreads();
  }
  int run = sm[tid] - s;
  for(int i=0;i<CH;i++){ of[base+i] = run; run += c[base+i]; }
  if(tid==255) of[NN] = run;
}

__global__ void csr_scatter(const int* __restrict__ dst, const int* __restrict__ src,
                            const int* __restrict__ offs, int* __restrict__ cur,
                            int* __restrict__ elist){
  int id = blockIdx.x*256 + threadIdx.x;
  int e = id >> 18;
  int d = dst[id];
  int pos = offs[e*(NN+1)+d] + atomicAdd(&cur[e*NN+d], 1);
  elist[e*EE + pos] = src[id];
}

// ---------------- transpose + bf16 convert (weights) ----------------
__global__ void tconv(const float* __restrict__ in, u16* __restrict__ out, int K, int Nc){
  __shared__ float tile[32][33];
  const long base = (long)blockIdx.z * K * Nc;
  const int k0 = blockIdx.x*32, n0 = blockIdx.y*32;
  const int tx = threadIdx.x, ty = threadIdx.y;
  for(int i=0;i<32;i+=8)
    tile[ty+i][tx] = in[base + (long)(k0+ty+i)*Nc + n0+tx];
  __syncthreads();
  for(int i=0;i<32;i+=8)
    out[base + (long)(n0+ty+i)*K + k0+tx] = f2b(tile[tx][ty+i]);
}

// ---------------- fold head transforms into K/V weights ----------------
__global__ void eff_w(const float* __restrict__ kw, const float* __restrict__ vw,
                      const float* __restrict__ kb, const float* __restrict__ vb,
                      const float* __restrict__ att, const float* __restrict__ val,
                      u16* __restrict__ qkvwt, float* __restrict__ qkvb){
  const int h = blockIdx.x, lt = blockIdx.y, kv = blockIdx.z;   // 8 x 4 x 2
  const int l = lt >> 1;
  const float* W = (kv ? vw : kw) + (long)lt*65536;
  const float* A = (kv ? val : att) + (long)lt*8192 + h*1024;
  const float* B = (kv ? vb : kb) + (long)lt*256 + h*32;
  __shared__ float As[32][33];
  for(int idx=threadIdx.x; idx<1024; idx+=256) As[idx>>5][idx&31] = A[idx];
  __syncthreads();
  const int r = threadIdx.x;
  float x[32];
  const float* wr = W + (long)r*256 + h*32;
  #pragma unroll
  for(int i=0;i<32;i++) x[i] = wr[i];
  u16* outb = qkvwt + (kv ? 524288 : 0) + (long)lt*65536;
  #pragma unroll 4
  for(int j=0;j<32;j++){
    float s = 0.f;
    #pragma unroll
    for(int i=0;i<32;i++) s = fmaf(x[i], As[i][j], s);
    outb[(h*32 + j)*256 + r] = f2b(s);
  }
  if (r < 32){
    float s = 0.f;
    #pragma unroll
    for(int i=0;i<32;i++) s = fmaf(B[i], As[i][r], s);
    qkvb[l*1536 + (kv ? 1024 : 0) + (lt&1)*256 + h*32 + r] = s;
  }
}

__global__ void pack_qb(const float* __restrict__ qb, float* __restrict__ qkvb){
  int i = blockIdx.x*256 + threadIdx.x;   // 1024 = L*T*256
  int l = i >> 9, r = i & 511;
  qkvb[l*1536 + 512 + r] = qb[l*512 + r];
}

// ---------------- rank-1 precompute for the linear posvect block ----------------
__global__ void uv_k(const float* __restrict__ lw, const float* __restrict__ lb,
                     const float* __restrict__ fcw,
                     float* __restrict__ ubuf, float* __restrict__ vbuf){
  const int by = blockIdx.x;            // 12
  const int j  = threadIdx.x;           // 256
  const float* fw = fcw + ((long)by*1024 + 256)*256 + j;
  const float* lwp = lw + by*256;
  const float* lbp = lb + by*256;
  float u = 0.f, v = 0.f;
  for(int h=0; h<256; h++){
    const float f = fw[(long)h*256];
    u = fmaf(lwp[h], f, u);
    v = fmaf(lbp[h], f, v);
  }
  ubuf[by*256+j] = u; vbuf[by*256+j] = v;
}

// ---------------- generic bf16-MFMA GEMM (swizzled LDS + async staging) ---------
// EPI: 0 = fp32 +bias; 1 = gelu->bf16; 4 = tanh dot w2 row-sum; 5 = residual mix + LayerNorm
// ASRC: 0 = fp32 A (VGPR cvt path); 1 = bf16 A (async global_load_lds).
// ZQKV: blockIdx.z = {K,Q,V}; K/V -> bf16 KV record, Q -> bf16.
// launch_bounds(256,2): (256,3+) spills the MFMA accumulators (R7: 674 MB
// scratch traffic, 2.5x regression). Do not raise.
template<int BM,int BN,int BK,int WM,int WN,int ASRC,int EPI,int ZQKV>
__global__ void __launch_bounds__(256,2)
gemm_k(const void* __restrict__ Av, const u16* __restrict__ Bt,
       const float* __restrict__ bias, void* Cv,
       int K, int lda, int ldc,
       long strideA, long strideB, long strideBias, long strideC,
       const float* resid, const float* __restrict__ resgate,
       const int* __restrict__ selp, u16* __restrict__ kvout,
       const float* __restrict__ lng, const float* __restrict__ lnb)
{
  static_assert(BK == 64, "swizzle assumes BK=64");
  constexpr int WTM = BM/WM, WTN = BN/WN;
  constexpr int RM = WTM/16, RN = WTN/16;
  __shared__ __align__(16) u16 lA[BM*64];
  __shared__ __align__(16) u16 lB[BN*64];

  const int tid = threadIdx.x;
  const int by  = blockIdx.y;
  const int m0  = blockIdx.x * BM;
  const int lane = tid & 63, wvi = tid >> 6;
  const int wr = wvi / WN, wc = wvi % WN;
  const int wr0 = wr * WTM, wc0 = wc * WTN;
  const int l16 = lane & 15, qd = lane >> 4;
  // per-lane source-column permutation implementing the XOR swizzle (see gl_lds16)
  const int csrc = (((lane & 7) ^ (lane >> 3)) << 3);

  int zq = 0; int boff = 0;
  if constexpr (ZQKV){
    zq = blockIdx.z;
    boff = zq*512;
  }

  long aoff = (long)by * strideA;
  if (selp) aoff += (long)selp[0] * strideA;
  const float* A32 = (const float*)Av;
  const u16*   A16 = (const u16*)Av;
  const u16*   Bp  = Bt + (long)by * strideB + (long)zq * 262144;

  f32x4 acc[RM][RN];
  #pragma unroll
  for(int i=0;i<RM;i++)
    #pragma unroll
    for(int j=0;j<RN;j++) acc[i][j] = (f32x4){0.f,0.f,0.f,0.f};

  for(int k0=0;k0<K;k0+=BK){
    if constexpr (ASRC == 0){
      for(int idx=tid; idx < BM*16; idx += 256){
        int r = idx >> 4, c = (idx & 15)*4;
        const float4 v = *(const float4*)(A32 + aoff + (long)(m0+r)*lda + k0 + c);
        uint2 o2; o2.x = pack2bf(v.x, v.y); o2.y = pack2bf(v.z, v.w);
        *(uint2*)&lA[swz64(r, c)] = o2;
      }
    } else {
      #pragma unroll
      for(int ch = wvi; ch < BM/8; ch += 4){
        const int r = ch*8 + (lane>>3);
        gl_lds16(A16 + aoff + (long)(m0+r)*lda + k0 + csrc, &lA[ch*512]);
      }
    }
    #pragma unroll
    for(int ch = wvi; ch < BN/8; ch += 4){
      const int n = ch*8 + (lane>>3);
      gl_lds16(Bp + (long)n*K + k0 + csrc, &lB[ch*512]);
    }
    __syncthreads();
    #pragma unroll
    for(int ks=0; ks<BK; ks+=32){
      bf16x8 af[RM], bfr[RN];
      #pragma unroll
      for(int i=0;i<RM;i++) af[i]  = *(const bf16x8*)&lA[swz64(wr0 + i*16 + l16, ks + qd*8)];
      #pragma unroll
      for(int j=0;j<RN;j++) bfr[j] = *(const bf16x8*)&lB[swz64(wc0 + j*16 + l16, ks + qd*8)];
      #pragma unroll
      for(int i=0;i<RM;i++)
        #pragma unroll
        for(int j=0;j<RN;j++)
          acc[i][j] = __builtin_amdgcn_mfma_f32_16x16x32_bf16(af[i], bfr[j], acc[i][j], 0,0,0);
    }
    __syncthreads();
  }

  if constexpr (EPI == 4){
    float* rsum = (float*)lA;   // alias dead A-tile (post-barrier safe)
    #pragma unroll
    for(int i=0;i<RM;i++){
      #pragma unroll
      for(int r=0;r<4;r++){
        float part = 0.f;
        #pragma unroll
        for(int jj=0;jj<RN;jj++){
          const int col = wc0 + jj*16 + l16;
          const float v = fast_tanh(acc[i][jj][r] + bias[boff + col]);
          part += v * resid[col];
        }
        part += __shfl_xor(part,1); part += __shfl_xor(part,2);
        part += __shfl_xor(part,4); part += __shfl_xor(part,8);
        if (l16 == 0) rsum[wc*BM + wr0 + i*16 + qd*4 + r] = part;
      }
    }
    __syncthreads();
    if (tid < BM){
      float s = 0.f;
      #pragma unroll
      for(int w=0;w<WN;w++) s += rsum[w*BM + tid];
      ((float*)Cv)[m0 + tid] = s;
    }
    return;
  } else if constexpr (EPI == 5){
    // residual mix -> LayerNorm fused; Cv == resid buffer (in-place per-row; barrier-separated)
    float* red1 = (float*)lA;            // WN*BM
    float* red2 = red1 + WN*BM;          // WN*BM
    float* muv  = red2 + WN*BM;          // BM*2
    const float alpha = 1.f/(1.f + __expf(-resgate[by]));
    #pragma unroll
    for(int i=0;i<RM;i++){
      #pragma unroll
      for(int r=0;r<4;r++){
        const int rloc = wr0 + i*16 + qd*4 + r;
        const int row = m0 + rloc;
        float s1 = 0.f, s2 = 0.f;
        #pragma unroll
        for(int j=0;j<RN;j++){
          const int col = wc0 + j*16 + l16;
          float v = acc[i][j][r] + bias[(long)by*strideBias + col];
          const float hv = resid[(long)by*strideC + (long)row*ldc + col];
          v = v*alpha + hv*(1.f - alpha);
          acc[i][j][r] = v;
          s1 += v; s2 += v*v;
        }
        s1 += __shfl_xor(s1,1); s1 += __shfl_xor(s1,2); s1 += __shfl_xor(s1,4); s1 += __shfl_xor(s1,8);
        s2 += __shfl_xor(s2,1); s2 += __shfl_xor(s2,2); s2 += __shfl_xor(s2,4); s2 += __shfl_xor(s2,8);
        if (l16 == 0){ red1[wc*BM + rloc] = s1; red2[wc*BM + rloc] = s2; }
      }
    }
    __syncthreads();
    if (tid < BM){
      float s1 = 0.f, s2 = 0.f;
      #pragma unroll
      for(int w=0;w<WN;w++){ s1 += red1[w*BM + tid]; s2 += red2[w*BM + tid]; }
      const float mu = s1*(1.f/256.f);
      const float var = s2*(1.f/256.f) - mu*mu;
      muv[tid*2]   = mu;
      muv[tid*2+1] = rsqrtf(fmaxf(var, 0.f) + 1e-5f);
    }
    __syncthreads();
    #pragma unroll
    for(int i=0;i<RM;i++){
      #pragma unroll
      for(int r=0;r<4;r++){
        const int rloc = wr0 + i*16 + qd*4 + r;
        const int row = m0 + rloc;
        const float mu = muv[rloc*2], rs = muv[rloc*2+1];
        #pragma unroll
        for(int j=0;j<RN;j++){
          const int col = wc0 + j*16 + l16;
          const float o = (acc[i][j][r]-mu)*rs*lng[by*256+col] + lnb[by*256+col];
          ((float*)Cv)[(long)by*strideC + (long)row*ldc + col] = o;
        }
      }
    }
    return;
  } else {
    #pragma unroll
    for(int i=0;i<RM;i++){
      #pragma unroll
      for(int j=0;j<RN;j++){
        const int col = wc0 + j*16 + l16;
        const float bv = bias[(long)by*strideBias + boff + col];
        #pragma unroll
        for(int r=0;r<4;r++){
          const int row = m0 + wr0 + i*16 + qd*4 + r;
          float v = acc[i][j][r] + bv;
          if constexpr (ZQKV){
            if (zq == 1)
              ((u16*)Cv)[(long)by*strideC + (long)row*ldc + col] = f2b(v);   // Q bf16
            else
              kvout[((long)by*NN + row)*512 + (zq==2 ? 256 : 0) + col] = f2b(v);
          } else {
            const long cidx = (long)by*strideC + (long)row*ldc + col;
            if constexpr (EPI == 0) ((float*)Cv)[cidx] = v;
            else ((u16*)Cv)[cidx] = f2b(gelu_f(v));
          }
        }
      }
    }
  }
}

// ---------------- posvect: K=768, swizzled LDS + async B staging ----------------
// acc[8][4] = 128 accumulator regs: any tighter occupancy bound spills (R7).
__global__ void __launch_bounds__(256,2)
posvect_k(const float* __restrict__ scalars,
          const float* __restrict__ ww, const float* __restrict__ wb,
          const float* __restrict__ sw, const float* __restrict__ sb,
          const float* __restrict__ gw, const float* __restrict__ gb,
          const u16* __restrict__ fwt, const float* __restrict__ fcb,
          const float* __restrict__ ubuf, const float* __restrict__ vbuf,
          u16* __restrict__ zb)
{
  __shared__ __align__(16) u16 lA[128*64];
  __shared__ __align__(16) u16 lB[256*64];
  __shared__ float xs[128];
  const int tid = threadIdx.x;
  const int by = blockIdx.y;
  const int t = by / 6, m = by % 6;
  const int m0 = blockIdx.x * 128;
  const int lane = tid & 63, wvi = tid >> 6;
  const int wc0 = wvi * 64;
  const int l16 = lane & 15, qd = lane >> 4;
  const int pofs = by * 256;
  const int csrc = (((lane & 7) ^ (lane >> 3)) << 3);

  if (tid < 128) xs[tid] = scalars[((long)t*NN + m0 + tid)*6 + m];

  const u16* Bp = fwt + (long)by * (1024*256);

  f32x4 acc[8][4];
  #pragma unroll
  for(int i=0;i<8;i++)
    #pragma unroll
    for(int j=0;j<4;j++) acc[i][j] = (f32x4){0.f,0.f,0.f,0.f};

  __syncthreads();

  const int jg   = tid & 7;
  const int row0 = tid >> 3;

  for(int kt=0; kt<12; kt++){
    const int k0 = kt*64 + (kt>=4 ? 256 : 0);        // skip the linear slab
    const int ia = (kt<4) ? 0 : ((kt<8) ? 2 : 3);
    // async B-tile staging first: loads fly while we generate A
    #pragma unroll
    for(int ch = wvi; ch < 32; ch += 4){
      const int n = ch*8 + (lane>>3);
      gl_lds16(Bp + (long)n*1024 + k0 + csrc, &lB[ch*512]);
    }
    const int hh = (k0 & 255) + jg*8;
    const float* wsel = ((ia==0)?ww:(ia==2)?sw:gw) + pofs;
    const float* bsel = ((ia==0)?wb:(ia==2)?sb:gb) + pofs;
    const float4 wa  = *(const float4*)(wsel + hh);
    const float4 wv2 = *(const float4*)(wsel + hh + 4);
    const float4 ba  = *(const float4*)(bsel + hh);
    const float4 bv2 = *(const float4*)(bsel + hh + 4);
    #pragma unroll
    for(int it=0; it<4; it++){
      const int row = row0 + it*32;
      const float x = xs[row];
      float y[8];
      y[0]=fmaf(x,wa.x,ba.x);   y[1]=fmaf(x,wa.y,ba.y);
      y[2]=fmaf(x,wa.z,ba.z);   y[3]=fmaf(x,wa.w,ba.w);
      y[4]=fmaf(x,wv2.x,bv2.x); y[5]=fmaf(x,wv2.y,bv2.y);
      y[6]=fmaf(x,wv2.z,bv2.z); y[7]=fmaf(x,wv2.w,bv2.w);
      float a[8];
      if (ia==0){
        #pragma unroll
        for(int i=0;i<8;i++) a[i] = __sinf(y[i]);
      } else if (ia==2){
        #pragma unroll
        for(int i=0;i<8;i++){
          const float ab = fabsf(y[i]);
          a[i] = fmaxf(y[i],0.f) + __logf(1.f + __expf(-ab));
        }
      } else {
        #pragma unroll
        for(int i=0;i<8;i++)
          a[i] = __builtin_amdgcn_rcpf(1.f + __expf(-y[i]));
      }
      uint4 pv;
      pv.x = pack2bf(a[0],a[1]); pv.y = pack2bf(a[2],a[3]);
      pv.z = pack2bf(a[4],a[5]); pv.w = pack2bf(a[6],a[7]);
      *(uint4*)&lA[swz64(row, jg*8)] = pv;
    }
    __syncthreads();
    #pragma unroll
    for(int ks=0; ks<64; ks+=32){
      bf16x8 af[8], bfr[4];
      #pragma unroll
      for(int i=0;i<8;i++) af[i]  = *(const bf16x8*)&lA[swz64(i*16 + l16, ks + qd*8)];
      #pragma unroll
      for(int jj=0;jj<4;jj++) bfr[jj] = *(const bf16x8*)&lB[swz64(wc0 + jj*16 + l16, ks + qd*8)];
      #pragma unroll
      for(int i=0;i<8;i++)
        #pragma unroll
        for(int jj=0;jj<4;jj++)
          acc[i][jj] = __builtin_amdgcn_mfma_f32_16x16x32_bf16(af[i], bfr[jj], acc[i][jj], 0,0,0);
    }
    __syncthreads();
  }

  #pragma unroll
  for(int i=0;i<8;i++){
    #pragma unroll
    for(int jj=0;jj<4;jj++){
      const int col = wc0 + jj*16 + l16;
      const float bv = fcb[pofs + col] + vbuf[pofs + col];
      const float uu = ubuf[pofs + col];
      #pragma unroll
      for(int r=0;r<4;r++){
        const int row = i*16 + qd*4 + r;
        const float v = acc[i][jj][r] + bv + xs[row]*uu;
        zb[((long)t*NN + m0 + row)*1792 + (m+1)*256 + col] = f2b(gelu_f(v));
      }
    }
  }
}

// ---------------- IMA combine ----------------
__global__ void ima_combine(const u16* __restrict__ zb, const float* __restrict__ wbuf,
                            float* __restrict__ H){
  const int row = blockIdx.x*4 + (threadIdx.x>>6);
  const int lane = threadIdx.x & 63;
  const float* w7 = wbuf + (long)row*7;
  float w[7]; float mx = -1e30f;
  #pragma unroll
  for(int m=0;m<7;m++){ w[m] = w7[m]; mx = fmaxf(mx, w[m]); }
  float sum = 0.f;
  #pragma unroll
  for(int m=0;m<7;m++){ w[m] = __expf(w[m]-mx); sum += w[m]; }
  const float inv = __builtin_amdgcn_rcpf(sum);
  float4 acc = {0,0,0,0};
  #pragma unroll
  for(int m=0;m<7;m++){
    const u16x4 z4 = *(const u16x4*)&zb[((long)row*7 + m)*256 + lane*4];
    const float p = w[m]*inv;
    acc.x += p*b2f(z4.x); acc.y += p*b2f(z4.y); acc.z += p*b2f(z4.z); acc.w += p*b2f(z4.w);
  }
  *(float4*)&H[(long)row*256 + lane*4] = acc;
}

// ---------------- attention aggregation: split-lane KV gather, unroll-8 ----------
// lanes 0-31: K dims half*8..+7 (head = half>>2); lanes 32-63: V dims half*8..+7.
__global__ void attn_agg(const u16* __restrict__ Q16, const u16* __restrict__ KV,
                         u16* __restrict__ AGG,
                         const int* __restrict__ offs, const int* __restrict__ elist,
                         const float* __restrict__ canon){
  const int e = blockIdx.y, dt = 1 - e;
  const int d = blockIdx.x*4 + (threadIdx.x>>6);
  const int lane = threadIdx.x & 63;
  const int half = lane & 31;
  const float scale = canon[e*8 + (half>>2)] * 0.17677669529663687f;

  const uint4 qv = *(const uint4*)&Q16[((long)dt*NN + d)*256 + half*8];
  float q[8];
  q[0]=b2f((u16)(qv.x&0xffff)); q[1]=b2f((u16)(qv.x>>16));
  q[2]=b2f((u16)(qv.y&0xffff)); q[3]=b2f((u16)(qv.y>>16));
  q[4]=b2f((u16)(qv.z&0xffff)); q[5]=b2f((u16)(qv.z>>16));
  q[6]=b2f((u16)(qv.w&0xffff)); q[7]=b2f((u16)(qv.w>>16));

  const int p0 = offs[e*(NN+1) + d], p1 = offs[e*(NN+1) + d + 1];
  const int* el = elist + (long)e*EE;
  const u16* KVb = KV + (long)e*NN*512;

  float acc[8] = {0,0,0,0,0,0,0,0};
  float den = 0.f;

  auto process = [&](const uint4 kv){
    float f[8];
    f[0]=b2f((u16)(kv.x&0xffff)); f[1]=b2f((u16)(kv.x>>16));
    f[2]=b2f((u16)(kv.y&0xffff)); f[3]=b2f((u16)(kv.y>>16));
    f[4]=b2f((u16)(kv.z&0xffff)); f[5]=b2f((u16)(kv.z>>16));
    f[6]=b2f((u16)(kv.w&0xffff)); f[7]=b2f((u16)(kv.w>>16));
    float dp = q[0]*f[0]+q[1]*f[1]+q[2]*f[2]+q[3]*f[3]
             + q[4]*f[4]+q[5]*f[5]+q[6]*f[6]+q[7]*f[7];
    dp += __shfl_xor(dp,1); dp += __shfl_xor(dp,2);
    const float w = __expf(dp*scale);        // valid in lanes 0-31
    const float wv = __shfl(w, half);        // whole wave active: broadcast K-lane weight
    den += w;
    #pragma unroll
    for(int j=0;j<8;j++) acc[j] += wv*f[j];  // meaningful in lanes 32-63
  };

  int p = p0;
  for(; p+8 <= p1; p += 8){
    uint4 kv[8];
    #pragma unroll
    for(int u=0;u<8;u++) kv[u] = *(const uint4*)&KVb[(long)el[p+u]*512 + lane*8];
    #pragma unroll
    for(int u=0;u<8;u++) process(kv[u]);
  }
  for(; p+2 <= p1; p += 2){
    const uint4 a = *(const uint4*)&KVb[(long)el[p]*512 + lane*8];
    const uint4 b = *(const uint4*)&KVb[(long)el[p+1]*512 + lane*8];
    process(a); process(b);
  }
  if (p < p1){
    const uint4 a = *(const uint4*)&KVb[(long)el[p]*512 + lane*8];
    process(a);
  }

  // Broadcast denominator to V lanes while ALL lanes are active
  // (bpermute from an EXEC-masked lane is undefined — the round-5 NaN).
  const float denv = __shfl(den, half);

  if (lane >= 32){
    uint4 o = {0,0,0,0};
    if (p1 > p0){
      const float rden = 1.f/denv;
      o.x = pack2bf(acc[0]*rden, acc[1]*rden);
      o.y = pack2bf(acc[2]*rden, acc[3]*rden);
      o.z = pack2bf(acc[4]*rden, acc[5]*rden);
      o.w = pack2bf(acc[6]*rden, acc[7]*rden);
    }
    *(uint4*)&AGG[((long)dt*NN + d)*256 + half*8] = o;
  }
}

// ---------------- host ----------------
extern "C" void kernel_launch(void* const* d_in, const int* in_sizes, int n_in,
                              void* d_out, int out_size, void* d_ws, size_t ws_size,
                              hipStream_t stream) {
  const float* node_ft = (const float*)d_in[0];
  const float* scalars = (const float*)d_in[1];
  const int*   src_idx = (const int*)d_in[2];
  const int*   dst_idx = (const int*)d_in[3];
  const float* proj_w  = (const float*)d_in[4];
  const float* proj_b  = (const float*)d_in[5];
  const float* pv_ww   = (const float*)d_in[6];
  const float* pv_wb   = (const float*)d_in[7];
  const float* pv_lw   = (const float*)d_in[8];
  const float* pv_lb   = (const float*)d_in[9];
  const float* pv_sw   = (const float*)d_in[10];
  const float* pv_sb   = (const float*)d_in[11];
  const float* pv_gw   = (const float*)d_in[12];
  const float* pv_gb   = (const float*)d_in[13];
  const float* pv_fcw  = (const float*)d_in[14];
  const float* pv_fcb  = (const float*)d_in[15];
  const float* ima_w1  = (const float*)d_in[16];
  const float* ima_b1  = (const float*)d_in[17];
  const float* ima_w2  = (const float*)d_in[18];
  const float* lyr_k_w = (const float*)d_in[19];
  const float* lyr_q_w = (const float*)d_in[20];
  const float* lyr_v_w = (const float*)d_in[21];
  const float* lyr_fc_w= (const float*)d_in[22];
  const float* lyr_k_b = (const float*)d_in[23];
  const float* lyr_q_b = (const float*)d_in[24];
  const float* lyr_v_b = (const float*)d_in[25];
  const float* lyr_fc_b= (const float*)d_in[26];
  const float* lyr_att_w=(const float*)d_in[27];
  const float* lyr_val_w=(const float*)d_in[28];
  const float* lyr_canon=(const float*)d_in[29];
  const float* lyr_res = (const float*)d_in[30];
  const float* lyr_ln_g= (const float*)d_in[31];
  const float* lyr_ln_b= (const float*)d_in[32];
  const float* out_w   = (const float*)d_in[33];
  const float* out_b   = (const float*)d_in[34];
  const int*   sel     = (const int*)d_in[35];
  float* outp = (float*)d_out;

  char* ws = (char*)d_ws;
  size_t o = 0;
  auto alloc = [&](size_t bytes)->char*{ char* p = ws + o; o = (o + bytes + 255) & ~(size_t)255; return p; };

  int*   cnt    = (int*)  alloc(2*NN*4);
  int*   cur    = (int*)  alloc(2*NN*4);
  int*   offs   = (int*)  alloc(2*(NN+1)*4);
  int*   elist  = (int*)  alloc(2*EE*4);
  u16*   projwt = (u16*)  alloc((size_t)TT*128*256*2);
  u16*   fwt    = (u16*)  alloc((size_t)TT*6*1024*256*2);
  u16*   imaw1t = (u16*)  alloc((size_t)256*128*2);
  u16*   qkvwt  = (u16*)  alloc((size_t)3*262144*2);   // [K_eff | Q | V_eff]
  u16*   fcwt   = (u16*)  alloc((size_t)4*256*256*2);
  u16*   outwt  = (u16*)  alloc((size_t)64*256*2);
  float* hbuf   = (float*)alloc((size_t)TT*NN*256*4);
  float* wbuf   = (float*)alloc((size_t)TT*NN*7*4);
  float* ubuf   = (float*)alloc((size_t)12*256*4);
  float* vbuf   = (float*)alloc((size_t)12*256*4);
  float* qkvb   = (float*)alloc((size_t)TT*3*2*256*4); // [l][z][t][256]
  char*  arena  = alloc((size_t)176160768);
  if (o > ws_size) return;

  u16*   zbuf  = (u16*)arena;                         // (T,N,7,256) bf16, phase A
  u16*   Qb16  = (u16*)arena;                         // phase B (zbuf dead after ima_combine)
  u16*   KVb   = (u16*)(arena + 16777216);            // (T,N,512) bf16 interleaved K|V
  u16*   AGG16 = (u16*)(arena + 50331648);            // (T,N,256) bf16

  // ---- CSR build ----
  hipMemsetAsync(cnt, 0, 2*NN*4, stream);
  hipMemsetAsync(cur, 0, 2*NN*4, stream);
  csr_hist   <<<2*EE/256, 256, 0, stream>>>(dst_idx, cnt);
  csr_scan   <<<2, 256, 0, stream>>>(cnt, offs);
  csr_scatter<<<2*EE/256, 256, 0, stream>>>(dst_idx, src_idx, offs, cur, elist);

  // ---- weights prep ----
  tconv<<<dim3( 4,8, 2), dim3(32,8), 0, stream>>>(proj_w,   projwt, 128, 256);
  tconv<<<dim3(32,8,12), dim3(32,8), 0, stream>>>(pv_fcw,   fwt,   1024, 256);
  tconv<<<dim3( 8,4, 1), dim3(32,8), 0, stream>>>(ima_w1,   imaw1t, 256, 128);
  tconv<<<dim3( 8,8, 4), dim3(32,8), 0, stream>>>(lyr_q_w,  qkvwt + 262144, 256, 256);
  tconv<<<dim3( 8,8, 4), dim3(32,8), 0, stream>>>(lyr_fc_w, fcwt,   256, 256);
  tconv<<<dim3( 8,2, 1), dim3(32,8), 0, stream>>>(out_w,    outwt,  256, 64);
  eff_w<<<dim3(8,4,2), 256, 0, stream>>>(lyr_k_w, lyr_v_w, lyr_k_b, lyr_v_b,
                                         lyr_att_w, lyr_val_w, qkvwt, qkvb);
  pack_qb<<<4, 256, 0, stream>>>(lyr_q_b, qkvb);
  uv_k <<<12, 256, 0, stream>>>(pv_lw, pv_lb, pv_fcw, ubuf, vbuf);

  // ---- h0 = gelu(node_ft @ proj_w + b) -> zbuf slot 0 ----
  gemm_k<64,256,64,1,4,0,1,0><<<dim3(256,TT), 256, 0, stream>>>(
      node_ft, projwt, proj_b, zbuf, 128, 128, 1792,
      (long)NN*128, 32768L, 256L, (long)NN*1792, nullptr, nullptr, nullptr, nullptr,
      nullptr, nullptr);

  // ---- posvect -> zbuf slots 1..6 ----
  posvect_k<<<dim3(128,12), 256, 0, stream>>>(scalars, pv_ww, pv_wb,
      pv_sw, pv_sb, pv_gw, pv_gb, fwt, pv_fcb, ubuf, vbuf, zbuf);

  // ---- IMA gate fused epilogue, then softmax-combine ----
  gemm_k<64,128,64,2,2,1,4,0><<<dim3(3584,1), 256, 0, stream>>>(
      zbuf, imaw1t, ima_b1, wbuf, 256, 256, 0,
      0L, 0L, 0L, 0L, ima_w2, nullptr, nullptr, nullptr, nullptr, nullptr);
  ima_combine<<<TT*NN/4, 256, 0, stream>>>(zbuf, wbuf, hbuf);

  // ---- layers ----
  for (int l = 0; l < 2; ++l){
    // merged K/Q/V with folded head transforms: z=0 K->KVb[..0..255], z=1 Q->Qb16, z=2 V->KVb[..256..511]
    gemm_k<64,256,64,1,4,0,0,1><<<dim3(256,TT,3), 256, 0, stream>>>(
        hbuf, qkvwt + (size_t)l*131072, qkvb + (size_t)l*1536, Qb16, 256, 256, 256,
        (long)NN*256, 65536L, 256L, (long)NN*256, nullptr, nullptr, nullptr, KVb,
        nullptr, nullptr);

    attn_agg<<<dim3(NN/4, 2), 256, 0, stream>>>(Qb16, KVb, AGG16, offs, elist,
                                                lyr_canon + l*2*8);

    // fc + residual mix + LayerNorm fused, in-place on hbuf
    gemm_k<64,256,64,1,4,1,5,0><<<dim3(256,TT), 256, 0, stream>>>(
        AGG16, fcwt + (size_t)l*2*65536, lyr_fc_b + l*2*256, hbuf, 256, 256, 256,
        (long)NN*256, 65536L, 256L, (long)NN*256, hbuf, lyr_res + l*2, nullptr, nullptr,
        lyr_ln_g + l*2*256, lyr_ln_b + l*2*256);
  }

  // ---- out = h[sel] @ out_w + out_b ----
  gemm_k<256,64,64,4,1,0,0,0><<<dim3(64,1), 256, 0, stream>>>(
      hbuf, outwt, out_b, outp, 256, 256, 64,
      (long)NN*256, 0L, 0L, 0L, nullptr, nullptr, sel, nullptr, nullptr, nullptr);

  (void)in_sizes; (void)n_in; (void)out_size;
}